// Round 10
// baseline (520.541 us; speedup 1.0000x reference)
//
#include <hip/hip_runtime.h>

// Transformer-XL relative multi-head attention + LayerNorm.
// Inputs/outputs fp32; internal MFMA compute in bf16.
// B=2, H=16, D=64, E=1024, QL=1024, ML=1024, KLEN=2048.
// rel_shift identity: unmasked (j<=i+ML): BDshift[i,j] = BD[i, j-i+QL-1].
// R10: proj_k/gemm_o switch to a REGISTER-prefetch pipeline: global loads
// for slab s+1 into VGPRs overlap MFMA on slab s; ds_write -> barrier at
// iteration top. LDS layout is bit-identical to R9 (same slots), only the
// transport changed. attn_k byte-identical to R9 (R5 body).

typedef __bf16 bf16;
typedef __bf16 bf16x4 __attribute__((ext_vector_type(4)));
typedef __bf16 bf16x8 __attribute__((ext_vector_type(8)));
typedef float f32x4 __attribute__((ext_vector_type(4)));

#define MFMA16(a, b, c) __builtin_amdgcn_mfma_f32_16x16x32_bf16((a), (b), (c), 0, 0, 0)

constexpr int E = 1024;
constexpr int NH = 16;
constexpr int DH = 64;
constexpr int QL = 1024;
constexpr int ML = 1024;
constexpr int KLEN = 2048;

// async 16B global->LDS. LDS dest is wave-uniform base + lane*16.
__device__ __forceinline__ void ldg2lds16(const bf16* g, bf16* l) {
    __builtin_amdgcn_global_load_lds(
        (const __attribute__((address_space(1))) unsigned int*)g,
        (__attribute__((address_space(3))) unsigned int*)l, 16, 0, 0);
}

// read a b128 fragment from an unpadded 64-col swizzled tile.
// physical 16B-chunk = logical chunk ^ (row & 7).
__device__ __forceinline__ bf16x8 frag8(const bf16* t, int row, int ch) {
    return *(const bf16x8*)(t + row * 64 + ((ch ^ (row & 7)) << 3));
}

// ---------------------------------------------------------------- prep
__global__ void prep_k(const float* __restrict__ member, const float* __restrict__ w,
                       bf16* __restrict__ cat) {
    int row = blockIdx.x;
    int b = row >> 11, jj = row & 2047;
    const float* src = (jj < ML) ? member + ((size_t)(b * ML + jj)) * E
                                 : w + ((size_t)(b * QL + (jj - ML))) * E;
    float4 f = *(const float4*)(src + threadIdx.x * 4);
    bf16x4 o;
    o[0] = (bf16)f.x; o[1] = (bf16)f.y; o[2] = (bf16)f.z; o[3] = (bf16)f.w;
    *(bf16x4*)(cat + (size_t)row * E + threadIdx.x * 4) = o;
}

// ---------------------------------------------------------------- transpose
__global__ void transpose_k(const float* __restrict__ Wq, const float* __restrict__ Wk,
                            const float* __restrict__ Wv, const float* __restrict__ Wr,
                            const float* __restrict__ Wo, bf16* __restrict__ WqT,
                            bf16* __restrict__ WkT, bf16* __restrict__ WvT,
                            bf16* __restrict__ WrT, bf16* __restrict__ WoT) {
    const float* W; bf16* WT;
    switch (blockIdx.z) {
        case 0: W = Wq; WT = WqT; break;
        case 1: W = Wk; WT = WkT; break;
        case 2: W = Wv; WT = WvT; break;
        case 3: W = Wr; WT = WrT; break;
        default: W = Wo; WT = WoT; break;
    }
    __shared__ float t[32][33];
    int bx = blockIdx.x * 32, by = blockIdx.y * 32;
    int x = threadIdx.x, y = threadIdx.y;
    for (int yy = y; yy < 32; yy += 8)
        t[yy][x] = W[(by + yy) * E + bx + x];
    __syncthreads();
    for (int yy = y; yy < 32; yy += 8)
        WT[(bx + yy) * E + by + x] = (bf16)t[x][yy];
}

// ---------------------------------------------------------------- projections
// Register-prefetch pipeline: regs hold slab s while MFMA runs on slab s-1.
// zone 0: Q (+biases, *1/32 folded -> Qw/Qr [b][h][i][d])
// zone 1: K -> Kh [b][h][j][d];  zone 2: V -> Vt [b][h][d][j];  zone 3: R -> RRh
__global__ __launch_bounds__(256) void proj_k(
    const bf16* __restrict__ cat, const float* __restrict__ r,
    const bf16* __restrict__ WqT, const bf16* __restrict__ WkT,
    const bf16* __restrict__ WvT, const bf16* __restrict__ WrT,
    const float* __restrict__ rwb, const float* __restrict__ rrb,
    bf16* __restrict__ Qw, bf16* __restrict__ Qr, bf16* __restrict__ Kh,
    bf16* __restrict__ Vt, bf16* __restrict__ RRh) {
    __shared__ __align__(16) bf16 As[128 * 64];
    __shared__ __align__(16) bf16 Bs[128 * 64];
    const int tid = threadIdx.x;
    const int wave = tid >> 6, lane = tid & 63, quad = lane >> 4, l16 = lane & 15;

    int id = blockIdx.x, zone, base;
    if (id < 128) { zone = 0; base = 0; }
    else if (id < 384) { zone = 1; base = 128; }
    else if (id < 640) { zone = 2; base = 384; }
    else { zone = 3; base = 640; }
    const int lid = id - base;
    const int bn = (lid & 7) * 128, bm = (lid >> 3) * 128;
    const bf16* Bt = (zone == 0) ? WqT : (zone == 1) ? WkT : (zone == 2) ? WvT : WrT;
    const int wm = (wave >> 1) * 64, wn = (wave & 1) * 64;

    f32x4 acc[4][4] = {};

    // per-lane invariant staging geometry (identical to R9's DMA addressing)
    int srow[4], scs[4];  // per issue: row 0..127, swizzled 16B chunk
    const bf16* arow[4];  // A source row base (bf16 zones)
    for (int issue = 0; issue < 4; ++issue) {
        int q = (issue * 4 + wave) * 64 + lane;
        srow[issue] = q >> 3;
        scs[issue] = (q & 7) ^ ((q >> 3) & 7);
        int gm = bm + srow[issue];
        if (zone == 0) {
            int b = gm >> 10;
            arow[issue] = cat + ((size_t)(b * 2048 + 1024 + (gm & 1023))) * E;
        } else {
            arow[issue] = cat + (size_t)gm * E;
        }
    }
    // zone 3 (fp32 A) row/col scheme (same as R9)
    const int z3row = tid >> 3, z3c = tid & 7;

    bf16x8 rA[4], rB[4];
    float4 zf0[4], zf1[4];

    auto loadRegs = [&](int s) {
        const int kk = s * 64;
        if (zone == 3) {
            for (int c = 0; c < 4; ++c) {
                int row = c * 32 + z3row;
                const float* ap = r + (size_t)(bm + row) * E + kk + z3c * 8;
                zf0[c] = *(const float4*)ap;
                zf1[c] = *(const float4*)(ap + 4);
            }
        } else {
            for (int issue = 0; issue < 4; ++issue)
                rA[issue] = *(const bf16x8*)(arow[issue] + kk + scs[issue] * 8);
        }
        for (int issue = 0; issue < 4; ++issue)
            rB[issue] = *(const bf16x8*)(Bt + (size_t)(bn + srow[issue]) * E + kk +
                                         scs[issue] * 8);
    };
    auto writeLDS = [&]() {
        if (zone == 3) {
            for (int c = 0; c < 4; ++c) {
                int row = c * 32 + z3row;
                bf16x8 v;
                v[0] = (bf16)zf0[c].x; v[1] = (bf16)zf0[c].y;
                v[2] = (bf16)zf0[c].z; v[3] = (bf16)zf0[c].w;
                v[4] = (bf16)zf1[c].x; v[5] = (bf16)zf1[c].y;
                v[6] = (bf16)zf1[c].z; v[7] = (bf16)zf1[c].w;
                *(bf16x8*)(As + row * 64 + ((z3c ^ (row & 7)) << 3)) = v;
            }
        } else {
            for (int issue = 0; issue < 4; ++issue)
                *(bf16x8*)(As + (issue * 4 + wave) * 512 + lane * 8) = rA[issue];
        }
        for (int issue = 0; issue < 4; ++issue)
            *(bf16x8*)(Bs + (issue * 4 + wave) * 512 + lane * 8) = rB[issue];
    };

    loadRegs(0);
    for (int s = 0; s < 16; ++s) {
        __syncthreads();  // previous MFMA done -> LDS free (no-op at s=0)
        writeLDS();
        __syncthreads();  // LDS ready
        if (s + 1 < 16) loadRegs(s + 1);  // in flight during MFMA
        for (int ks = 0; ks < 64; ks += 32) {
            bf16x8 af[4], bfr[4];
            for (int mt = 0; mt < 4; ++mt)
                af[mt] = frag8(As, wm + mt * 16 + l16, (ks >> 3) + quad);
            for (int nt = 0; nt < 4; ++nt)
                bfr[nt] = frag8(Bs, wn + nt * 16 + l16, (ks >> 3) + quad);
            for (int mt = 0; mt < 4; ++mt)
                for (int nt = 0; nt < 4; ++nt)
                    acc[mt][nt] = MFMA16(af[mt], bfr[nt], acc[mt][nt]);
        }
    }

    if (zone == 2) {
        __syncthreads();  // all MFMA reads of LDS done before reuse
        // Vt[b][h][d][j]: per-wave 64x64 swizzled LDS transpose, then b128 stores.
        bf16* buf = ((wave < 2) ? As : Bs) + (wave & 1) * 4096;
        for (int mt = 0; mt < 4; ++mt)
            for (int nt = 0; nt < 4; ++nt)
                for (int rr = 0; rr < 4; ++rr) {
                    int lr = mt * 16 + quad * 4 + rr;  // local j
                    int lc = nt * 16 + l16;            // local d
                    buf[lr * 64 + (((lc >> 3) ^ (lr & 7)) << 3) + (lc & 7)] =
                        (bf16)acc[mt][nt][rr];
                }
        int h = (bn + wn) >> 6;
        int gmw = bm + wm;
        int b = gmw >> 11, jb = gmw & 2047;
        for (int dp = 0; dp < 8; ++dp) {
            int dl = dp * 8 + (lane >> 3);
            int jl = (lane & 7) * 8;
            bf16x8 tmp;
            for (int jj = 0; jj < 8; ++jj) {
                int rw = jl + jj;
                tmp[jj] = buf[rw * 64 + (((dl >> 3) ^ (rw & 7)) << 3) + (dl & 7)];
            }
            *(bf16x8*)(Vt + (((size_t)(b * NH + h) * DH + dl) * KLEN) + jb + jl) = tmp;
        }
        return;
    }

    for (int mt = 0; mt < 4; ++mt)
        for (int nt = 0; nt < 4; ++nt)
            for (int rr = 0; rr < 4; ++rr) {
                int row = bm + wm + mt * 16 + quad * 4 + rr;
                int col = bn + wn + nt * 16 + l16;
                float v = acc[mt][nt][rr];
                if (zone == 0) {
                    int b = row >> 10, i = row & 1023;
                    int h = col >> 6, d = col & 63;
                    size_t o = (((size_t)(b * NH + h) * QL) + i) * DH + d;
                    Qw[o] = (bf16)((v + rwb[col]) * 0.03125f);  // fold 1/sqrt(E)
                    Qr[o] = (bf16)((v + rrb[col]) * 0.03125f);
                } else if (zone == 1) {
                    int b = row >> 11, j = row & 2047;
                    int h = col >> 6, d = col & 63;
                    Kh[(((size_t)(b * NH + h) * KLEN) + j) * DH + d] = (bf16)v;
                } else {
                    int h = col >> 6, d = col & 63;
                    RRh[(((size_t)h * KLEN) + row) * DH + d] = (bf16)v;
                }
            }
}

// ---------------------------------------------------------------- attention
// EXACT R5 body (known-passing, 77 us). 512 blocks, 256 thr, each wave 16
// q-rows. Fixed-shift softmax (M=0): p = exp(s), s = Qw'.K + Qr'.RR (1/32
// pre-folded). l accumulated per-lane, reduced once at the end. Mask applied
// only on the final j-tile. K/V double-buffered; RR 3-slot rolling ring.
__global__ __launch_bounds__(256) void attn_k(
    const bf16* __restrict__ Qw, const bf16* __restrict__ Qr,
    const bf16* __restrict__ Kh, const bf16* __restrict__ Vt,
    const bf16* __restrict__ RRh, bf16* __restrict__ AttO) {
    __shared__ __align__(16) bf16 Ks[2][64 * 64];
    __shared__ __align__(16) bf16 Vs[2][64 * 64];
    __shared__ __align__(16) bf16 RRing[3][64 * 64];
    __shared__ __align__(16) bf16 UB[4][16 * 88];  // per-wave BD window + P

    const int tid = threadIdx.x;
    const int wave = tid >> 6, lane = tid & 63, quad = lane >> 4, l16 = lane & 15;
    const int id = blockIdx.x;
    const int b = id >> 8, h = (id >> 4) & 15;
    const int qt = (id < 256) ? (id & 15) : (15 - (id & 15));
    const int i0 = qt * 64;

    const bf16* Qwb = Qw + ((size_t)(b * NH + h) * QL) * DH;
    const bf16* Qrb = Qr + ((size_t)(b * NH + h) * QL) * DH;
    const bf16* Kb = Kh + ((size_t)(b * NH + h) * KLEN) * DH;
    const bf16* Vb = Vt + ((size_t)(b * NH + h) * DH) * KLEN;  // [d][j]
    const bf16* Rb = RRh + ((size_t)h * KLEN) * DH;

    bf16x8 qw0, qw1, qr0, qr1;
    {
        int i = i0 + wave * 16 + l16;
        qw0 = *(const bf16x8*)(Qwb + (size_t)i * DH + quad * 8);
        qw1 = *(const bf16x8*)(Qwb + (size_t)i * DH + 32 + quad * 8);
        qr0 = *(const bf16x8*)(Qrb + (size_t)i * DH + quad * 8);
        qr1 = *(const bf16x8*)(Qrb + (size_t)i * DH + 32 + quad * 8);
    }

    float lpart[4] = {0.f, 0.f, 0.f, 0.f};
    f32x4 oacc[4] = {};

    const int ntiles = qt + 17;
    const int cbase = 15 - qt;  // global RR chunk of window start at t=0
    const int ptbase = 3 - wave;

    auto stage_kv = [&](int t) {
        const int j0 = t * 64;
        bf16* Kd = Ks[t & 1];
        bf16* Vd = Vs[t & 1];
        for (int issue = 0; issue < 2; ++issue) {
            int q = (issue * 4 + wave) * 64 + lane;
            int row = q >> 3, cs = (q & 7) ^ ((q >> 3) & 7);
            ldg2lds16(Kb + (size_t)(j0 + row) * DH + cs * 8,
                      Kd + (issue * 4 + wave) * 512);
            ldg2lds16(Vb + (size_t)row * KLEN + j0 + cs * 8,
                      Vd + (issue * 4 + wave) * 512);
        }
    };
    auto stage_rr = [&](int c) {  // load global 64-row chunk c into slot c%3
        bf16* Rd = RRing[c % 3];
        for (int issue = 0; issue < 2; ++issue) {
            int q = (issue * 4 + wave) * 64 + lane;
            int row = q >> 3, cs = (q & 7) ^ ((q >> 3) & 7);
            int pr = c * 64 + row;
            pr = pr > KLEN - 1 ? KLEN - 1 : pr;  // clamped rows feed masked cols
            ldg2lds16(Rb + (size_t)pr * DH + cs * 8, Rd + (issue * 4 + wave) * 512);
        }
    };

    stage_kv(0);
    stage_rr(cbase);
    stage_rr(cbase + 1);
    __syncthreads();

    for (int t = 0; t < ntiles; ++t) {
        const bf16* Kt = Ks[t & 1];
        const bf16* Vl = Vs[t & 1];
        const bf16* Rlo = RRing[(cbase + t) % 3];
        const bf16* Rhi = RRing[(cbase + t + 1) % 3];
        if (t + 1 < ntiles) {
            stage_kv(t + 1);
            stage_rr(cbase + t + 2);
        }

        // BD = Qr @ RRwindow^T (this wave's 5 pt tiles) -> UB compact
        for (int pi = 0; pi < 5; ++pi) {
            int pt = ptbase + pi;
            const bf16* Rsrc = (pt < 4) ? Rlo : Rhi;
            int rrow = (pt & 3) * 16 + l16;
            f32x4 bacc = {};
            bacc = MFMA16(qr0, frag8(Rsrc, rrow, quad), bacc);
            bacc = MFMA16(qr1, frag8(Rsrc, rrow, 4 + quad), bacc);
            for (int rr = 0; rr < 4; ++rr)
                UB[wave][(quad * 4 + rr) * 88 + pi * 16 + l16] = (bf16)bacc[rr];
        }

        // AC = Qw @ K^T
        f32x4 sacc[4];
        for (int nt = 0; nt < 4; ++nt) {
            f32x4 a = {};
            a = MFMA16(qw0, frag8(Kt, nt * 16 + l16, quad), a);
            a = MFMA16(qw1, frag8(Kt, nt * 16 + l16, 4 + quad), a);
            sacc[nt] = a;
        }

        // p = exp(AC+BD); only final tile needs the causal mask
        float sv[4][4];
        const bool lastt = (t == ntiles - 1);
        for (int nt = 0; nt < 4; ++nt)
            for (int rr = 0; rr < 4; ++rr) {
                int lr = quad * 4 + rr;
                int col = nt * 16 + l16 + 15 - lr;
                float bdv = (float)UB[wave][lr * 88 + col];
                float p = __expf(sacc[nt][rr] + bdv);
                if (lastt) {
                    int i = i0 + wave * 16 + lr;
                    int j = t * 64 + nt * 16 + l16;
                    if (j > i + ML) p = 0.f;
                }
                sv[nt][rr] = p;
                lpart[rr] += p;
            }

        // P: C-layout -> UB cols 0..63 (bds consumed) -> A-layout
        for (int nt = 0; nt < 4; ++nt)
            for (int rr = 0; rr < 4; ++rr)
                UB[wave][(quad * 4 + rr) * 88 + nt * 16 + l16] = (bf16)sv[nt][rr];

        for (int c = 0; c < 2; ++c) {
            bf16x8 pa = *(const bf16x8*)(&UB[wave][l16 * 88 + c * 32 + quad * 8]);
            for (int nt = 0; nt < 4; ++nt) {
                bf16x8 vb = frag8(Vl, nt * 16 + l16, c * 4 + quad);
                oacc[nt] = MFMA16(pa, vb, oacc[nt]);
            }
        }
        __syncthreads();  // prefetched t+1 complete + all reads of t done
    }

    // deferred l reduction (once, not per tile)
    float linv[4];
    for (int rr = 0; rr < 4; ++rr) {
        float v = lpart[rr];
        v += __shfl_xor(v, 1);
        v += __shfl_xor(v, 2);
        v += __shfl_xor(v, 4);
        v += __shfl_xor(v, 8);
        linv[rr] = 1.f / v;
    }

    for (int nt = 0; nt < 4; ++nt)
        for (int rr = 0; rr < 4; ++rr) {
            int i = i0 + wave * 16 + quad * 4 + rr;
            int d = nt * 16 + l16;
            AttO[((size_t)(b * QL + i)) * E + h * DH + d] =
                (bf16)(oacc[nt][rr] * linv[rr]);
        }
}

// ---------------------------------------------------------------- out proj
// split-K x2: z-half computes partial Xp[z] (fp32, no resid). ln_k sums.
// Register-prefetch pipeline (same transformation as proj_k).
__global__ __launch_bounds__(256) void gemm_o(
    const bf16* __restrict__ A, const bf16* __restrict__ Bt,
    float* __restrict__ Xp) {
    __shared__ __align__(16) bf16 As[128 * 64];
    __shared__ __align__(16) bf16 Bs[128 * 64];
    const int tid = threadIdx.x;
    const int wave = tid >> 6, lane = tid & 63, quad = lane >> 4, l16 = lane & 15;
    const int bm = blockIdx.y * 128, bn = blockIdx.x * 128;
    const int kbase = blockIdx.z * 512;
    const int wm = (wave >> 1) * 64, wn = (wave & 1) * 64;

    f32x4 acc[4][4] = {};

    int srow[4], scs[4];
    for (int issue = 0; issue < 4; ++issue) {
        int q = (issue * 4 + wave) * 64 + lane;
        srow[issue] = q >> 3;
        scs[issue] = (q & 7) ^ ((q >> 3) & 7);
    }
    bf16x8 rA[4], rB[4];
    auto loadRegs = [&](int s) {
        const int kk = kbase + s * 64;
        for (int issue = 0; issue < 4; ++issue) {
            rA[issue] =
                *(const bf16x8*)(A + (size_t)(bm + srow[issue]) * E + kk + scs[issue] * 8);
            rB[issue] =
                *(const bf16x8*)(Bt + (size_t)(bn + srow[issue]) * E + kk + scs[issue] * 8);
        }
    };
    auto writeLDS = [&]() {
        for (int issue = 0; issue < 4; ++issue) {
            *(bf16x8*)(As + (issue * 4 + wave) * 512 + lane * 8) = rA[issue];
            *(bf16x8*)(Bs + (issue * 4 + wave) * 512 + lane * 8) = rB[issue];
        }
    };

    loadRegs(0);
    for (int s = 0; s < 8; ++s) {
        __syncthreads();
        writeLDS();
        __syncthreads();
        if (s + 1 < 8) loadRegs(s + 1);
        for (int ks = 0; ks < 64; ks += 32) {
            bf16x8 af[4], bfr[4];
            for (int mt = 0; mt < 4; ++mt)
                af[mt] = frag8(As, wm + mt * 16 + l16, (ks >> 3) + quad);
            for (int nt = 0; nt < 4; ++nt)
                bfr[nt] = frag8(Bs, wn + nt * 16 + l16, (ks >> 3) + quad);
            for (int mt = 0; mt < 4; ++mt)
                for (int nt = 0; nt < 4; ++nt)
                    acc[mt][nt] = MFMA16(af[mt], bfr[nt], acc[mt][nt]);
        }
    }

    float* Xz = Xp + (size_t)blockIdx.z * 2048 * 1024;
    for (int mt = 0; mt < 4; ++mt)
        for (int nt = 0; nt < 4; ++nt)
            for (int rr = 0; rr < 4; ++rr) {
                int row = bm + wm + mt * 16 + quad * 4 + rr;
                int col = bn + wn + nt * 16 + l16;
                Xz[(size_t)row * E + col] = acc[mt][nt][rr];
            }
}

// ---------------------------------------------------------------- layernorm
// x = Xp0 + Xp1 + resid(w); out = LN(x)*gamma+beta
__global__ __launch_bounds__(256) void ln_k(const float* __restrict__ Xp,
                                            const float* __restrict__ resid,
                                            const float* __restrict__ gamma,
                                            const float* __restrict__ beta,
                                            float* __restrict__ out) {
    const int row = blockIdx.x;
    const int tid = threadIdx.x;
    const float* x0 = Xp + (size_t)row * E;
    const float* x1 = Xp + (size_t)2048 * 1024 + (size_t)row * E;
    const float* xr = resid + (size_t)row * E;
    float xv[4], s = 0.f, q = 0.f;
    for (int c = 0; c < 4; ++c) {
        int col = c * 256 + tid;
        float v = x0[col] + x1[col] + xr[col];
        xv[c] = v;
        s += v;
        q += v * v;
    }
    for (int off = 32; off > 0; off >>= 1) {
        s += __shfl_down(s, off);
        q += __shfl_down(q, off);
    }
    __shared__ float rs[4], rq[4];
    int wave = tid >> 6, lane = tid & 63;
    if (lane == 0) { rs[wave] = s; rq[wave] = q; }
    __syncthreads();
    float S = rs[0] + rs[1] + rs[2] + rs[3];
    float Q = rq[0] + rq[1] + rq[2] + rq[3];
    float mean = S * (1.f / E);
    float var = fmaxf(Q * (1.f / E) - mean * mean, 0.f);
    float rstd = rsqrtf(var + 1e-3f);
    for (int c = 0; c < 4; ++c) {
        int col = c * 256 + tid;
        out[(size_t)row * E + col] =
            (xv[c] - mean) * rstd * gamma[col] + beta[col];
    }
}

// ---------------------------------------------------------------- launch
extern "C" void kernel_launch(void* const* d_in, const int* in_sizes, int n_in,
                              void* d_out, int out_size, void* d_ws,
                              size_t ws_size, hipStream_t stream) {
    (void)in_sizes; (void)n_in; (void)out_size; (void)ws_size;
    const float* w = (const float*)d_in[0];
    const float* r = (const float*)d_in[1];
    const float* rwb = (const float*)d_in[3];
    const float* rrb = (const float*)d_in[4];
    const float* member = (const float*)d_in[5];
    const float* Wq = (const float*)d_in[6];
    const float* Wk = (const float*)d_in[7];
    const float* Wv = (const float*)d_in[8];
    const float* Wr = (const float*)d_in[9];
    const float* Wo = (const float*)d_in[10];
    const float* gamma = (const float*)d_in[11];
    const float* beta = (const float*)d_in[12];
    float* out = (float*)d_out;

    char* ws = (char*)d_ws;
    const size_t MB = 1024 * 1024;
    bf16* WqT = (bf16*)(ws + 0 * MB);   // 0-8: WqT/WkT/WvT/WrT (dead after proj)
    bf16* WkT = (bf16*)(ws + 2 * MB);
    bf16* WvT = (bf16*)(ws + 4 * MB);
    bf16* WrT = (bf16*)(ws + 6 * MB);
    bf16* WoT = (bf16*)(ws + 8 * MB);   // live until gemm_o
    bf16* cat = (bf16*)(ws + 10 * MB);  // 10-18; dead after proj_k
    bf16* AttO = (bf16*)(ws + 14 * MB); // 14-18 (over cat 2nd half)
    bf16* Qw = (bf16*)(ws + 18 * MB);
    bf16* Qr = (bf16*)(ws + 22 * MB);
    float* Xp = (float*)(ws + 18 * MB); // 18-34 over Qw/Qr/Kh (dead after attn)
    bf16* Kh = (bf16*)(ws + 26 * MB);
    bf16* Vt = (bf16*)(ws + 34 * MB);
    bf16* RRh = (bf16*)(ws + 42 * MB);
    // high-water: 46 MB

    prep_k<<<4096, 256, 0, stream>>>(member, w, cat);
    transpose_k<<<dim3(32, 32, 5), dim3(32, 8), 0, stream>>>(
        Wq, Wk, Wv, Wr, Wo, WqT, WkT, WvT, WrT, WoT);

    proj_k<<<768, 256, 0, stream>>>(cat, r, WqT, WkT, WvT, WrT, rwb, rrb, Qw,
                                    Qr, Kh, Vt, RRh);

    attn_k<<<512, 256, 0, stream>>>(Qw, Qr, Kh, Vt, RRh, AttO);

    gemm_o<<<dim3(8, 16, 2), 256, 0, stream>>>(AttO, WoT, Xp);
    ln_k<<<2048, 256, 0, stream>>>(Xp, w, gamma, beta, out);
}

// Round 11
// 268.664 us; speedup vs baseline: 1.9375x; 1.9375x over previous
//
#include <hip/hip_runtime.h>

// Transformer-XL relative multi-head attention + LayerNorm.
// Inputs/outputs fp32; internal MFMA compute in bf16.
// B=2, H=16, D=64, E=1024, QL=1024, ML=1024, KLEN=2048.
// rel_shift identity: unmasked (j<=i+ML): BDshift[i,j] = BD[i, j-i+QL-1].
// R11: R9 base (best: 261.8 us). proj_k loop structure FROZEN (R6/R10
// pipelining both spilled: WRITE_SIZE ~1 GB). Changes: (1) K+V zones merged
// (A staged once, 64 MFMA per barrier-drain, dual acc; heavy blocks first
// for LPT packing); (2) prep_k+transpose_k merged into one launch.

typedef __bf16 bf16;
typedef __bf16 bf16x4 __attribute__((ext_vector_type(4)));
typedef __bf16 bf16x8 __attribute__((ext_vector_type(8)));
typedef float f32x4 __attribute__((ext_vector_type(4)));

#define MFMA16(a, b, c) __builtin_amdgcn_mfma_f32_16x16x32_bf16((a), (b), (c), 0, 0, 0)

constexpr int E = 1024;
constexpr int NH = 16;
constexpr int DH = 64;
constexpr int QL = 1024;
constexpr int ML = 1024;
constexpr int KLEN = 2048;

// async 16B global->LDS. LDS dest is wave-uniform base + lane*16.
__device__ __forceinline__ void ldg2lds16(const bf16* g, bf16* l) {
    __builtin_amdgcn_global_load_lds(
        (const __attribute__((address_space(1))) unsigned int*)g,
        (__attribute__((address_space(3))) unsigned int*)l, 16, 0, 0);
}

// read a b128 fragment from an unpadded 64-col swizzled tile.
// physical 16B-chunk = logical chunk ^ (row & 7).
__device__ __forceinline__ bf16x8 frag8(const bf16* t, int row, int ch) {
    return *(const bf16x8*)(t + row * 64 + ((ch ^ (row & 7)) << 3));
}

// ---------------------------------------------------------------- pre
// blocks 0..5119: 5 weight transposes (WT[n][k] = bf16(W[k][n]))
// blocks 5120..9215: cat[b][jj][e] = bf16(concat(member, w))
__global__ void pre_k(const float* __restrict__ Wq, const float* __restrict__ Wk,
                      const float* __restrict__ Wv, const float* __restrict__ Wr,
                      const float* __restrict__ Wo, const float* __restrict__ member,
                      const float* __restrict__ w, bf16* __restrict__ WqT,
                      bf16* __restrict__ WkT, bf16* __restrict__ WvT,
                      bf16* __restrict__ WrT, bf16* __restrict__ WoT,
                      bf16* __restrict__ cat) {
    const int id = blockIdx.x;
    const int tid = threadIdx.x;
    __shared__ float t[32][33];
    if (id < 5120) {
        const float* W; bf16* WT;
        switch (id >> 10) {
            case 0: W = Wq; WT = WqT; break;
            case 1: W = Wk; WT = WkT; break;
            case 2: W = Wv; WT = WvT; break;
            case 3: W = Wr; WT = WrT; break;
            default: W = Wo; WT = WoT; break;
        }
        int xy = id & 1023;
        int bx = (xy & 31) * 32, by = (xy >> 5) * 32;
        int x = tid & 31, y = tid >> 5;
        for (int yy = y; yy < 32; yy += 8)
            t[yy][x] = W[(by + yy) * E + bx + x];
        __syncthreads();
        for (int yy = y; yy < 32; yy += 8)
            WT[(bx + yy) * E + by + x] = (bf16)t[x][yy];
    } else {
        int row = id - 5120;
        int b = row >> 11, jj = row & 2047;
        const float* src = (jj < ML) ? member + ((size_t)(b * ML + jj)) * E
                                     : w + ((size_t)(b * QL + (jj - ML))) * E;
        float4 f = *(const float4*)(src + tid * 4);
        bf16x4 o;
        o[0] = (bf16)f.x; o[1] = (bf16)f.y; o[2] = (bf16)f.z; o[3] = (bf16)f.w;
        *(bf16x4*)(cat + (size_t)row * E + tid * 4) = o;
    }
}

// ---------------------------------------------------------------- projections
// Single-buffer two-barrier staging (R9-frozen loop structure).
// zone KV (blocks 0-255, heavy, dispatched first): A staged once, both
//   WkT/WvT tiles staged, dual acc -> Kh [b][h][j][d] + Vt [b][h][d][j]
// zone Q  (blocks 256-383): +biases, *1/32 folded -> Qw/Qr [b][h][i][d]
// zone R  (blocks 384-511): fp32 A manual staging -> RRh [h][p][d]
__global__ __launch_bounds__(256) void proj_k(
    const bf16* __restrict__ cat, const float* __restrict__ r,
    const bf16* __restrict__ WqT, const bf16* __restrict__ WkT,
    const bf16* __restrict__ WvT, const bf16* __restrict__ WrT,
    const float* __restrict__ rwb, const float* __restrict__ rrb,
    bf16* __restrict__ Qw, bf16* __restrict__ Qr, bf16* __restrict__ Kh,
    bf16* __restrict__ Vt, bf16* __restrict__ RRh) {
    __shared__ __align__(16) bf16 As[128 * 64];
    __shared__ __align__(16) bf16 Bs[128 * 64];
    __shared__ __align__(16) bf16 Cs[128 * 64];  // V weights (zone KV only)
    const int tid = threadIdx.x;
    const int wave = tid >> 6, lane = tid & 63, quad = lane >> 4, l16 = lane & 15;

    const int id = blockIdx.x;
    const int zone = (id < 256) ? 0 : (id < 384) ? 1 : 2;  // 0=KV 1=Q 2=R
    const int lid = (zone == 0) ? id : (zone == 1) ? id - 256 : id - 384;
    const int bn = (lid & 7) * 128, bm = (lid >> 3) * 128;
    const bf16* Bt = (zone == 0) ? WkT : (zone == 1) ? WqT : WrT;
    const int wm = (wave >> 1) * 64, wn = (wave & 1) * 64;

    f32x4 acc[4][4] = {};   // K / Q / R accumulator
    f32x4 acc2[4][4] = {};  // V accumulator (zone KV)

    for (int kk = 0; kk < E; kk += 64) {
        if (zone == 2) {  // fp32 A: manual convert+write (swizzled slots)
            int srw = tid >> 3, cch = tid & 7;
            for (int c = 0; c < 4; ++c) {
                int row = c * 32 + srw;
                const float* ap = r + (size_t)(bm + row) * E + kk + cch * 8;
                float4 f0 = *(const float4*)ap;
                float4 f1 = *(const float4*)(ap + 4);
                bf16x8 v;
                v[0] = (bf16)f0.x; v[1] = (bf16)f0.y; v[2] = (bf16)f0.z; v[3] = (bf16)f0.w;
                v[4] = (bf16)f1.x; v[5] = (bf16)f1.y; v[6] = (bf16)f1.z; v[7] = (bf16)f1.w;
                *(bf16x8*)(As + row * 64 + ((cch ^ (row & 7)) << 3)) = v;
            }
        } else {
            for (int issue = 0; issue < 4; ++issue) {
                int q = (issue * 4 + wave) * 64 + lane;
                int row = q >> 3, cs = (q & 7) ^ ((q >> 3) & 7);
                int gm = bm + row;
                const bf16* ap;
                if (zone == 1) {
                    int b = gm >> 10;
                    ap = cat + ((size_t)(b * 2048 + 1024 + (gm & 1023))) * E;
                } else {
                    ap = cat + (size_t)gm * E;
                }
                ldg2lds16(ap + kk + cs * 8, As + (issue * 4 + wave) * 512);
            }
        }
        for (int issue = 0; issue < 4; ++issue) {
            int q = (issue * 4 + wave) * 64 + lane;
            int row = q >> 3, cs = (q & 7) ^ ((q >> 3) & 7);
            ldg2lds16(Bt + (size_t)(bn + row) * E + kk + cs * 8,
                      Bs + (issue * 4 + wave) * 512);
        }
        if (zone == 0) {
            for (int issue = 0; issue < 4; ++issue) {
                int q = (issue * 4 + wave) * 64 + lane;
                int row = q >> 3, cs = (q & 7) ^ ((q >> 3) & 7);
                ldg2lds16(WvT + (size_t)(bn + row) * E + kk + cs * 8,
                          Cs + (issue * 4 + wave) * 512);
            }
        }
        __syncthreads();
        for (int ks = 0; ks < 64; ks += 32) {
            bf16x8 af[4], bfr[4];
            for (int mt = 0; mt < 4; ++mt)
                af[mt] = frag8(As, wm + mt * 16 + l16, (ks >> 3) + quad);
            for (int nt = 0; nt < 4; ++nt)
                bfr[nt] = frag8(Bs, wn + nt * 16 + l16, (ks >> 3) + quad);
            for (int mt = 0; mt < 4; ++mt)
                for (int nt = 0; nt < 4; ++nt)
                    acc[mt][nt] = MFMA16(af[mt], bfr[nt], acc[mt][nt]);
            if (zone == 0) {
                bf16x8 cfr[4];
                for (int nt = 0; nt < 4; ++nt)
                    cfr[nt] = frag8(Cs, wn + nt * 16 + l16, (ks >> 3) + quad);
                for (int mt = 0; mt < 4; ++mt)
                    for (int nt = 0; nt < 4; ++nt)
                        acc2[mt][nt] = MFMA16(af[mt], cfr[nt], acc2[mt][nt]);
            }
        }
        __syncthreads();
    }

    if (zone == 0) {
        // K epilogue from acc
        for (int mt = 0; mt < 4; ++mt)
            for (int nt = 0; nt < 4; ++nt)
                for (int rr = 0; rr < 4; ++rr) {
                    int row = bm + wm + mt * 16 + quad * 4 + rr;
                    int col = bn + wn + nt * 16 + l16;
                    int b = row >> 11, j = row & 2047;
                    int h = col >> 6, d = col & 63;
                    Kh[(((size_t)(b * NH + h) * KLEN) + j) * DH + d] =
                        (bf16)acc[mt][nt][rr];
                }
        // V epilogue from acc2: per-wave 64x64 swizzled LDS transpose.
        // (trailing loop barrier guarantees LDS is free)
        bf16* buf = ((wave < 2) ? As : Bs) + (wave & 1) * 4096;
        for (int mt = 0; mt < 4; ++mt)
            for (int nt = 0; nt < 4; ++nt)
                for (int rr = 0; rr < 4; ++rr) {
                    int lr = mt * 16 + quad * 4 + rr;  // local j
                    int lc = nt * 16 + l16;            // local d
                    buf[lr * 64 + (((lc >> 3) ^ (lr & 7)) << 3) + (lc & 7)] =
                        (bf16)acc2[mt][nt][rr];
                }
        int h = (bn + wn) >> 6;
        int gmw = bm + wm;
        int b = gmw >> 11, jb = gmw & 2047;
        for (int dp = 0; dp < 8; ++dp) {
            int dl = dp * 8 + (lane >> 3);
            int jl = (lane & 7) * 8;
            bf16x8 tmp;
            for (int jj = 0; jj < 8; ++jj) {
                int rw = jl + jj;
                tmp[jj] = buf[rw * 64 + (((dl >> 3) ^ (rw & 7)) << 3) + (dl & 7)];
            }
            *(bf16x8*)(Vt + (((size_t)(b * NH + h) * DH + dl) * KLEN) + jb + jl) = tmp;
        }
        return;
    }

    for (int mt = 0; mt < 4; ++mt)
        for (int nt = 0; nt < 4; ++nt)
            for (int rr = 0; rr < 4; ++rr) {
                int row = bm + wm + mt * 16 + quad * 4 + rr;
                int col = bn + wn + nt * 16 + l16;
                float v = acc[mt][nt][rr];
                if (zone == 1) {
                    int b = row >> 10, i = row & 1023;
                    int h = col >> 6, d = col & 63;
                    size_t o = (((size_t)(b * NH + h) * QL) + i) * DH + d;
                    Qw[o] = (bf16)((v + rwb[col]) * 0.03125f);  // fold 1/sqrt(E)
                    Qr[o] = (bf16)((v + rrb[col]) * 0.03125f);
                } else {
                    int h = col >> 6, d = col & 63;
                    RRh[(((size_t)h * KLEN) + row) * DH + d] = (bf16)v;
                }
            }
}

// ---------------------------------------------------------------- attention
// EXACT R5 body (known-passing, 77 us). 512 blocks, 256 thr, each wave 16
// q-rows. Fixed-shift softmax (M=0): p = exp(s), s = Qw'.K + Qr'.RR (1/32
// pre-folded). l accumulated per-lane, reduced once at the end. Mask applied
// only on the final j-tile. K/V double-buffered; RR 3-slot rolling ring.
__global__ __launch_bounds__(256) void attn_k(
    const bf16* __restrict__ Qw, const bf16* __restrict__ Qr,
    const bf16* __restrict__ Kh, const bf16* __restrict__ Vt,
    const bf16* __restrict__ RRh, bf16* __restrict__ AttO) {
    __shared__ __align__(16) bf16 Ks[2][64 * 64];
    __shared__ __align__(16) bf16 Vs[2][64 * 64];
    __shared__ __align__(16) bf16 RRing[3][64 * 64];
    __shared__ __align__(16) bf16 UB[4][16 * 88];  // per-wave BD window + P

    const int tid = threadIdx.x;
    const int wave = tid >> 6, lane = tid & 63, quad = lane >> 4, l16 = lane & 15;
    const int id = blockIdx.x;
    const int b = id >> 8, h = (id >> 4) & 15;
    const int qt = (id < 256) ? (id & 15) : (15 - (id & 15));
    const int i0 = qt * 64;

    const bf16* Qwb = Qw + ((size_t)(b * NH + h) * QL) * DH;
    const bf16* Qrb = Qr + ((size_t)(b * NH + h) * QL) * DH;
    const bf16* Kb = Kh + ((size_t)(b * NH + h) * KLEN) * DH;
    const bf16* Vb = Vt + ((size_t)(b * NH + h) * DH) * KLEN;  // [d][j]
    const bf16* Rb = RRh + ((size_t)h * KLEN) * DH;

    bf16x8 qw0, qw1, qr0, qr1;
    {
        int i = i0 + wave * 16 + l16;
        qw0 = *(const bf16x8*)(Qwb + (size_t)i * DH + quad * 8);
        qw1 = *(const bf16x8*)(Qwb + (size_t)i * DH + 32 + quad * 8);
        qr0 = *(const bf16x8*)(Qrb + (size_t)i * DH + quad * 8);
        qr1 = *(const bf16x8*)(Qrb + (size_t)i * DH + 32 + quad * 8);
    }

    float lpart[4] = {0.f, 0.f, 0.f, 0.f};
    f32x4 oacc[4] = {};

    const int ntiles = qt + 17;
    const int cbase = 15 - qt;  // global RR chunk of window start at t=0
    const int ptbase = 3 - wave;

    auto stage_kv = [&](int t) {
        const int j0 = t * 64;
        bf16* Kd = Ks[t & 1];
        bf16* Vd = Vs[t & 1];
        for (int issue = 0; issue < 2; ++issue) {
            int q = (issue * 4 + wave) * 64 + lane;
            int row = q >> 3, cs = (q & 7) ^ ((q >> 3) & 7);
            ldg2lds16(Kb + (size_t)(j0 + row) * DH + cs * 8,
                      Kd + (issue * 4 + wave) * 512);
            ldg2lds16(Vb + (size_t)row * KLEN + j0 + cs * 8,
                      Vd + (issue * 4 + wave) * 512);
        }
    };
    auto stage_rr = [&](int c) {  // load global 64-row chunk c into slot c%3
        bf16* Rd = RRing[c % 3];
        for (int issue = 0; issue < 2; ++issue) {
            int q = (issue * 4 + wave) * 64 + lane;
            int row = q >> 3, cs = (q & 7) ^ ((q >> 3) & 7);
            int pr = c * 64 + row;
            pr = pr > KLEN - 1 ? KLEN - 1 : pr;  // clamped rows feed masked cols
            ldg2lds16(Rb + (size_t)pr * DH + cs * 8, Rd + (issue * 4 + wave) * 512);
        }
    };

    stage_kv(0);
    stage_rr(cbase);
    stage_rr(cbase + 1);
    __syncthreads();

    for (int t = 0; t < ntiles; ++t) {
        const bf16* Kt = Ks[t & 1];
        const bf16* Vl = Vs[t & 1];
        const bf16* Rlo = RRing[(cbase + t) % 3];
        const bf16* Rhi = RRing[(cbase + t + 1) % 3];
        if (t + 1 < ntiles) {
            stage_kv(t + 1);
            stage_rr(cbase + t + 2);
        }

        // BD = Qr @ RRwindow^T (this wave's 5 pt tiles) -> UB compact
        for (int pi = 0; pi < 5; ++pi) {
            int pt = ptbase + pi;
            const bf16* Rsrc = (pt < 4) ? Rlo : Rhi;
            int rrow = (pt & 3) * 16 + l16;
            f32x4 bacc = {};
            bacc = MFMA16(qr0, frag8(Rsrc, rrow, quad), bacc);
            bacc = MFMA16(qr1, frag8(Rsrc, rrow, 4 + quad), bacc);
            for (int rr = 0; rr < 4; ++rr)
                UB[wave][(quad * 4 + rr) * 88 + pi * 16 + l16] = (bf16)bacc[rr];
        }

        // AC = Qw @ K^T
        f32x4 sacc[4];
        for (int nt = 0; nt < 4; ++nt) {
            f32x4 a = {};
            a = MFMA16(qw0, frag8(Kt, nt * 16 + l16, quad), a);
            a = MFMA16(qw1, frag8(Kt, nt * 16 + l16, 4 + quad), a);
            sacc[nt] = a;
        }

        // p = exp(AC+BD); only final tile needs the causal mask
        float sv[4][4];
        const bool lastt = (t == ntiles - 1);
        for (int nt = 0; nt < 4; ++nt)
            for (int rr = 0; rr < 4; ++rr) {
                int lr = quad * 4 + rr;
                int col = nt * 16 + l16 + 15 - lr;
                float bdv = (float)UB[wave][lr * 88 + col];
                float p = __expf(sacc[nt][rr] + bdv);
                if (lastt) {
                    int i = i0 + wave * 16 + lr;
                    int j = t * 64 + nt * 16 + l16;
                    if (j > i + ML) p = 0.f;
                }
                sv[nt][rr] = p;
                lpart[rr] += p;
            }

        // P: C-layout -> UB cols 0..63 (bds consumed) -> A-layout
        for (int nt = 0; nt < 4; ++nt)
            for (int rr = 0; rr < 4; ++rr)
                UB[wave][(quad * 4 + rr) * 88 + nt * 16 + l16] = (bf16)sv[nt][rr];

        for (int c = 0; c < 2; ++c) {
            bf16x8 pa = *(const bf16x8*)(&UB[wave][l16 * 88 + c * 32 + quad * 8]);
            for (int nt = 0; nt < 4; ++nt) {
                bf16x8 vb = frag8(Vl, nt * 16 + l16, c * 4 + quad);
                oacc[nt] = MFMA16(pa, vb, oacc[nt]);
            }
        }
        __syncthreads();  // prefetched t+1 complete + all reads of t done
    }

    // deferred l reduction (once, not per tile)
    float linv[4];
    for (int rr = 0; rr < 4; ++rr) {
        float v = lpart[rr];
        v += __shfl_xor(v, 1);
        v += __shfl_xor(v, 2);
        v += __shfl_xor(v, 4);
        v += __shfl_xor(v, 8);
        linv[rr] = 1.f / v;
    }

    for (int nt = 0; nt < 4; ++nt)
        for (int rr = 0; rr < 4; ++rr) {
            int i = i0 + wave * 16 + quad * 4 + rr;
            int d = nt * 16 + l16;
            AttO[((size_t)(b * QL + i)) * E + h * DH + d] =
                (bf16)(oacc[nt][rr] * linv[rr]);
        }
}

// ---------------------------------------------------------------- out proj
// split-K x2: z-half computes partial Xp[z] (fp32, no resid). ln_k sums.
// Single-buffer two-barrier staging (R9-frozen).
__global__ __launch_bounds__(256) void gemm_o(
    const bf16* __restrict__ A, const bf16* __restrict__ Bt,
    float* __restrict__ Xp) {
    __shared__ __align__(16) bf16 As[128 * 64];
    __shared__ __align__(16) bf16 Bs[128 * 64];
    const int tid = threadIdx.x;
    const int wave = tid >> 6, lane = tid & 63, quad = lane >> 4, l16 = lane & 15;
    const int bm = blockIdx.y * 128, bn = blockIdx.x * 128;
    const int kbase = blockIdx.z * 512;
    const int wm = (wave >> 1) * 64, wn = (wave & 1) * 64;

    f32x4 acc[4][4] = {};

    for (int s = 0; s < 8; ++s) {
        const int kk = kbase + s * 64;
        for (int issue = 0; issue < 4; ++issue) {
            int q = (issue * 4 + wave) * 64 + lane;
            int row = q >> 3, cs = (q & 7) ^ ((q >> 3) & 7);
            ldg2lds16(A + (size_t)(bm + row) * E + kk + cs * 8,
                      As + (issue * 4 + wave) * 512);
            ldg2lds16(Bt + (size_t)(bn + row) * E + kk + cs * 8,
                      Bs + (issue * 4 + wave) * 512);
        }
        __syncthreads();
        for (int ks = 0; ks < 64; ks += 32) {
            bf16x8 af[4], bfr[4];
            for (int mt = 0; mt < 4; ++mt)
                af[mt] = frag8(As, wm + mt * 16 + l16, (ks >> 3) + quad);
            for (int nt = 0; nt < 4; ++nt)
                bfr[nt] = frag8(Bs, wn + nt * 16 + l16, (ks >> 3) + quad);
            for (int mt = 0; mt < 4; ++mt)
                for (int nt = 0; nt < 4; ++nt)
                    acc[mt][nt] = MFMA16(af[mt], bfr[nt], acc[mt][nt]);
        }
        __syncthreads();
    }

    float* Xz = Xp + (size_t)blockIdx.z * 2048 * 1024;
    for (int mt = 0; mt < 4; ++mt)
        for (int nt = 0; nt < 4; ++nt)
            for (int rr = 0; rr < 4; ++rr) {
                int row = bm + wm + mt * 16 + quad * 4 + rr;
                int col = bn + wn + nt * 16 + l16;
                Xz[(size_t)row * E + col] = acc[mt][nt][rr];
            }
}

// ---------------------------------------------------------------- layernorm
// x = Xp0 + Xp1 + resid(w); out = LN(x)*gamma+beta
__global__ __launch_bounds__(256) void ln_k(const float* __restrict__ Xp,
                                            const float* __restrict__ resid,
                                            const float* __restrict__ gamma,
                                            const float* __restrict__ beta,
                                            float* __restrict__ out) {
    const int row = blockIdx.x;
    const int tid = threadIdx.x;
    const float* x0 = Xp + (size_t)row * E;
    const float* x1 = Xp + (size_t)2048 * 1024 + (size_t)row * E;
    const float* xr = resid + (size_t)row * E;
    float xv[4], s = 0.f, q = 0.f;
    for (int c = 0; c < 4; ++c) {
        int col = c * 256 + tid;
        float v = x0[col] + x1[col] + xr[col];
        xv[c] = v;
        s += v;
        q += v * v;
    }
    for (int off = 32; off > 0; off >>= 1) {
        s += __shfl_down(s, off);
        q += __shfl_down(q, off);
    }
    __shared__ float rs[4], rq[4];
    int wave = tid >> 6, lane = tid & 63;
    if (lane == 0) { rs[wave] = s; rq[wave] = q; }
    __syncthreads();
    float S = rs[0] + rs[1] + rs[2] + rs[3];
    float Q = rq[0] + rq[1] + rq[2] + rq[3];
    float mean = S * (1.f / E);
    float var = fmaxf(Q * (1.f / E) - mean * mean, 0.f);
    float rstd = rsqrtf(var + 1e-3f);
    for (int c = 0; c < 4; ++c) {
        int col = c * 256 + tid;
        out[(size_t)row * E + col] =
            (xv[c] - mean) * rstd * gamma[col] + beta[col];
    }
}

// ---------------------------------------------------------------- launch
extern "C" void kernel_launch(void* const* d_in, const int* in_sizes, int n_in,
                              void* d_out, int out_size, void* d_ws,
                              size_t ws_size, hipStream_t stream) {
    (void)in_sizes; (void)n_in; (void)out_size; (void)ws_size;
    const float* w = (const float*)d_in[0];
    const float* r = (const float*)d_in[1];
    const float* rwb = (const float*)d_in[3];
    const float* rrb = (const float*)d_in[4];
    const float* member = (const float*)d_in[5];
    const float* Wq = (const float*)d_in[6];
    const float* Wk = (const float*)d_in[7];
    const float* Wv = (const float*)d_in[8];
    const float* Wr = (const float*)d_in[9];
    const float* Wo = (const float*)d_in[10];
    const float* gamma = (const float*)d_in[11];
    const float* beta = (const float*)d_in[12];
    float* out = (float*)d_out;

    char* ws = (char*)d_ws;
    const size_t MB = 1024 * 1024;
    bf16* WqT = (bf16*)(ws + 0 * MB);   // 0-8: WqT/WkT/WvT/WrT (dead after proj)
    bf16* WkT = (bf16*)(ws + 2 * MB);
    bf16* WvT = (bf16*)(ws + 4 * MB);
    bf16* WrT = (bf16*)(ws + 6 * MB);
    bf16* WoT = (bf16*)(ws + 8 * MB);   // live until gemm_o
    bf16* cat = (bf16*)(ws + 10 * MB);  // 10-18; dead after proj_k
    bf16* AttO = (bf16*)(ws + 14 * MB); // 14-18 (over cat 2nd half)
    bf16* Qw = (bf16*)(ws + 18 * MB);
    bf16* Qr = (bf16*)(ws + 22 * MB);
    float* Xp = (float*)(ws + 18 * MB); // 18-34 over Qw/Qr/Kh (dead after attn)
    bf16* Kh = (bf16*)(ws + 26 * MB);
    bf16* Vt = (bf16*)(ws + 34 * MB);
    bf16* RRh = (bf16*)(ws + 42 * MB);
    // high-water: 46 MB

    pre_k<<<9216, 256, 0, stream>>>(Wq, Wk, Wv, Wr, Wo, member, w, WqT, WkT,
                                    WvT, WrT, WoT, cat);

    proj_k<<<512, 256, 0, stream>>>(cat, r, WqT, WkT, WvT, WrT, rwb, rrb, Qw,
                                    Qr, Kh, Vt, RRh);

    attn_k<<<512, 256, 0, stream>>>(Qw, Qr, Kh, Vt, RRh, AttO);

    gemm_o<<<dim3(8, 16, 2), 256, 0, stream>>>(AttO, WoT, Xp);
    ln_k<<<2048, 256, 0, stream>>>(Xp, w, gamma, beta, out);
}

// Round 12
// 262.262 us; speedup vs baseline: 1.9848x; 1.0244x over previous
//
#include <hip/hip_runtime.h>

// Transformer-XL relative multi-head attention + LayerNorm.
// Inputs/outputs fp32; internal MFMA compute in bf16.
// B=2, H=16, D=64, E=1024, QL=1024, ML=1024, KLEN=2048.
// rel_shift identity: unmasked (j<=i+ML): BDshift[i,j] = BD[i, j-i+QL-1].
// R12: best-measured assembly. proj_k/gemm_o/ln_k/attn_k byte-identical to
// R9 (261.8 us best); pre_k merged launch from R11 (verified passing).
// proj_k loop structure FROZEN: R6 (LDS dbuf), R10 (reg prefetch) spilled
// to 1 GB scratch writes; R11 (KV merge) lost occupancy. R9 = optimum.

typedef __bf16 bf16;
typedef __bf16 bf16x4 __attribute__((ext_vector_type(4)));
typedef __bf16 bf16x8 __attribute__((ext_vector_type(8)));
typedef float f32x4 __attribute__((ext_vector_type(4)));

#define MFMA16(a, b, c) __builtin_amdgcn_mfma_f32_16x16x32_bf16((a), (b), (c), 0, 0, 0)

constexpr int E = 1024;
constexpr int NH = 16;
constexpr int DH = 64;
constexpr int QL = 1024;
constexpr int ML = 1024;
constexpr int KLEN = 2048;

// async 16B global->LDS. LDS dest is wave-uniform base + lane*16.
__device__ __forceinline__ void ldg2lds16(const bf16* g, bf16* l) {
    __builtin_amdgcn_global_load_lds(
        (const __attribute__((address_space(1))) unsigned int*)g,
        (__attribute__((address_space(3))) unsigned int*)l, 16, 0, 0);
}

// read a b128 fragment from an unpadded 64-col swizzled tile.
// physical 16B-chunk = logical chunk ^ (row & 7).
__device__ __forceinline__ bf16x8 frag8(const bf16* t, int row, int ch) {
    return *(const bf16x8*)(t + row * 64 + ((ch ^ (row & 7)) << 3));
}

// ---------------------------------------------------------------- pre
// blocks 0..5119: 5 weight transposes (WT[n][k] = bf16(W[k][n]))
// blocks 5120..9215: cat[b][jj][e] = bf16(concat(member, w))
__global__ void pre_k(const float* __restrict__ Wq, const float* __restrict__ Wk,
                      const float* __restrict__ Wv, const float* __restrict__ Wr,
                      const float* __restrict__ Wo, const float* __restrict__ member,
                      const float* __restrict__ w, bf16* __restrict__ WqT,
                      bf16* __restrict__ WkT, bf16* __restrict__ WvT,
                      bf16* __restrict__ WrT, bf16* __restrict__ WoT,
                      bf16* __restrict__ cat) {
    const int id = blockIdx.x;
    const int tid = threadIdx.x;
    __shared__ float t[32][33];
    if (id < 5120) {
        const float* W; bf16* WT;
        switch (id >> 10) {
            case 0: W = Wq; WT = WqT; break;
            case 1: W = Wk; WT = WkT; break;
            case 2: W = Wv; WT = WvT; break;
            case 3: W = Wr; WT = WrT; break;
            default: W = Wo; WT = WoT; break;
        }
        int xy = id & 1023;
        int bx = (xy & 31) * 32, by = (xy >> 5) * 32;
        int x = tid & 31, y = tid >> 5;
        for (int yy = y; yy < 32; yy += 8)
            t[yy][x] = W[(by + yy) * E + bx + x];
        __syncthreads();
        for (int yy = y; yy < 32; yy += 8)
            WT[(bx + yy) * E + by + x] = (bf16)t[x][yy];
    } else {
        int row = id - 5120;
        int b = row >> 11, jj = row & 2047;
        const float* src = (jj < ML) ? member + ((size_t)(b * ML + jj)) * E
                                     : w + ((size_t)(b * QL + (jj - ML))) * E;
        float4 f = *(const float4*)(src + tid * 4);
        bf16x4 o;
        o[0] = (bf16)f.x; o[1] = (bf16)f.y; o[2] = (bf16)f.z; o[3] = (bf16)f.w;
        *(bf16x4*)(cat + (size_t)row * E + tid * 4) = o;
    }
}

// ---------------------------------------------------------------- projections
// EXACT R9 body. Single-buffer two-barrier staging.
// zone 0: Q (+biases, *1/32 folded -> Qw/Qr [b][h][i][d])
// zone 1: K -> Kh [b][h][j][d];  zone 2: V -> Vt [b][h][d][j];  zone 3: R -> RRh
__global__ __launch_bounds__(256) void proj_k(
    const bf16* __restrict__ cat, const float* __restrict__ r,
    const bf16* __restrict__ WqT, const bf16* __restrict__ WkT,
    const bf16* __restrict__ WvT, const bf16* __restrict__ WrT,
    const float* __restrict__ rwb, const float* __restrict__ rrb,
    bf16* __restrict__ Qw, bf16* __restrict__ Qr, bf16* __restrict__ Kh,
    bf16* __restrict__ Vt, bf16* __restrict__ RRh) {
    __shared__ __align__(16) bf16 As[128 * 64];
    __shared__ __align__(16) bf16 Bs[128 * 64];
    const int tid = threadIdx.x;
    const int wave = tid >> 6, lane = tid & 63, quad = lane >> 4, l16 = lane & 15;

    int id = blockIdx.x, zone, base;
    if (id < 128) { zone = 0; base = 0; }
    else if (id < 384) { zone = 1; base = 128; }
    else if (id < 640) { zone = 2; base = 384; }
    else { zone = 3; base = 640; }
    const int lid = id - base;
    const int bn = (lid & 7) * 128, bm = (lid >> 3) * 128;
    const bf16* Bt = (zone == 0) ? WqT : (zone == 1) ? WkT : (zone == 2) ? WvT : WrT;
    const int wm = (wave >> 1) * 64, wn = (wave & 1) * 64;

    f32x4 acc[4][4] = {};

    for (int kk = 0; kk < E; kk += 64) {
        if (zone == 3) {  // fp32 A: manual convert+write (swizzled slots)
            int srw = tid >> 3, cch = tid & 7;
            for (int c = 0; c < 4; ++c) {
                int row = c * 32 + srw;
                const float* ap = r + (size_t)(bm + row) * E + kk + cch * 8;
                float4 f0 = *(const float4*)ap;
                float4 f1 = *(const float4*)(ap + 4);
                bf16x8 v;
                v[0] = (bf16)f0.x; v[1] = (bf16)f0.y; v[2] = (bf16)f0.z; v[3] = (bf16)f0.w;
                v[4] = (bf16)f1.x; v[5] = (bf16)f1.y; v[6] = (bf16)f1.z; v[7] = (bf16)f1.w;
                *(bf16x8*)(As + row * 64 + ((cch ^ (row & 7)) << 3)) = v;
            }
        } else {
            for (int issue = 0; issue < 4; ++issue) {
                int q = (issue * 4 + wave) * 64 + lane;
                int row = q >> 3, cs = (q & 7) ^ ((q >> 3) & 7);
                int gm = bm + row;
                const bf16* ap;
                if (zone == 0) {
                    int b = gm >> 10;
                    ap = cat + ((size_t)(b * 2048 + 1024 + (gm & 1023))) * E;
                } else {
                    ap = cat + (size_t)gm * E;
                }
                ldg2lds16(ap + kk + cs * 8, As + (issue * 4 + wave) * 512);
            }
        }
        for (int issue = 0; issue < 4; ++issue) {
            int q = (issue * 4 + wave) * 64 + lane;
            int row = q >> 3, cs = (q & 7) ^ ((q >> 3) & 7);
            ldg2lds16(Bt + (size_t)(bn + row) * E + kk + cs * 8,
                      Bs + (issue * 4 + wave) * 512);
        }
        __syncthreads();
        for (int ks = 0; ks < 64; ks += 32) {
            bf16x8 af[4], bfr[4];
            for (int mt = 0; mt < 4; ++mt)
                af[mt] = frag8(As, wm + mt * 16 + l16, (ks >> 3) + quad);
            for (int nt = 0; nt < 4; ++nt)
                bfr[nt] = frag8(Bs, wn + nt * 16 + l16, (ks >> 3) + quad);
            for (int mt = 0; mt < 4; ++mt)
                for (int nt = 0; nt < 4; ++nt)
                    acc[mt][nt] = MFMA16(af[mt], bfr[nt], acc[mt][nt]);
        }
        __syncthreads();
    }

    if (zone == 2) {
        // Vt[b][h][d][j]: per-wave 64x64 swizzled LDS transpose, then b128 stores.
        bf16* buf = ((wave < 2) ? As : Bs) + (wave & 1) * 4096;
        for (int mt = 0; mt < 4; ++mt)
            for (int nt = 0; nt < 4; ++nt)
                for (int rr = 0; rr < 4; ++rr) {
                    int lr = mt * 16 + quad * 4 + rr;  // local j
                    int lc = nt * 16 + l16;            // local d
                    buf[lr * 64 + (((lc >> 3) ^ (lr & 7)) << 3) + (lc & 7)] =
                        (bf16)acc[mt][nt][rr];
                }
        int h = (bn + wn) >> 6;
        int gmw = bm + wm;
        int b = gmw >> 11, jb = gmw & 2047;
        for (int dp = 0; dp < 8; ++dp) {
            int dl = dp * 8 + (lane >> 3);
            int jl = (lane & 7) * 8;
            bf16x8 tmp;
            for (int jj = 0; jj < 8; ++jj) {
                int rw = jl + jj;
                tmp[jj] = buf[rw * 64 + (((dl >> 3) ^ (rw & 7)) << 3) + (dl & 7)];
            }
            *(bf16x8*)(Vt + (((size_t)(b * NH + h) * DH + dl) * KLEN) + jb + jl) = tmp;
        }
        return;
    }

    for (int mt = 0; mt < 4; ++mt)
        for (int nt = 0; nt < 4; ++nt)
            for (int rr = 0; rr < 4; ++rr) {
                int row = bm + wm + mt * 16 + quad * 4 + rr;
                int col = bn + wn + nt * 16 + l16;
                float v = acc[mt][nt][rr];
                if (zone == 0) {
                    int b = row >> 10, i = row & 1023;
                    int h = col >> 6, d = col & 63;
                    size_t o = (((size_t)(b * NH + h) * QL) + i) * DH + d;
                    Qw[o] = (bf16)((v + rwb[col]) * 0.03125f);  // fold 1/sqrt(E)
                    Qr[o] = (bf16)((v + rrb[col]) * 0.03125f);
                } else if (zone == 1) {
                    int b = row >> 11, j = row & 2047;
                    int h = col >> 6, d = col & 63;
                    Kh[(((size_t)(b * NH + h) * KLEN) + j) * DH + d] = (bf16)v;
                } else {
                    int h = col >> 6, d = col & 63;
                    RRh[(((size_t)h * KLEN) + row) * DH + d] = (bf16)v;
                }
            }
}

// ---------------------------------------------------------------- attention
// EXACT R5/R9 body (known-passing, ~78 us). 512 blocks, 256 thr, each wave
// 16 q-rows. Fixed-shift softmax (M=0): p = exp(s), s = Qw'.K + Qr'.RR (1/32
// pre-folded). l accumulated per-lane, reduced once at the end. Mask applied
// only on the final j-tile. K/V double-buffered; RR 3-slot rolling ring.
__global__ __launch_bounds__(256) void attn_k(
    const bf16* __restrict__ Qw, const bf16* __restrict__ Qr,
    const bf16* __restrict__ Kh, const bf16* __restrict__ Vt,
    const bf16* __restrict__ RRh, bf16* __restrict__ AttO) {
    __shared__ __align__(16) bf16 Ks[2][64 * 64];
    __shared__ __align__(16) bf16 Vs[2][64 * 64];
    __shared__ __align__(16) bf16 RRing[3][64 * 64];
    __shared__ __align__(16) bf16 UB[4][16 * 88];  // per-wave BD window + P

    const int tid = threadIdx.x;
    const int wave = tid >> 6, lane = tid & 63, quad = lane >> 4, l16 = lane & 15;
    const int id = blockIdx.x;
    const int b = id >> 8, h = (id >> 4) & 15;
    const int qt = (id < 256) ? (id & 15) : (15 - (id & 15));
    const int i0 = qt * 64;

    const bf16* Qwb = Qw + ((size_t)(b * NH + h) * QL) * DH;
    const bf16* Qrb = Qr + ((size_t)(b * NH + h) * QL) * DH;
    const bf16* Kb = Kh + ((size_t)(b * NH + h) * KLEN) * DH;
    const bf16* Vb = Vt + ((size_t)(b * NH + h) * DH) * KLEN;  // [d][j]
    const bf16* Rb = RRh + ((size_t)h * KLEN) * DH;

    bf16x8 qw0, qw1, qr0, qr1;
    {
        int i = i0 + wave * 16 + l16;
        qw0 = *(const bf16x8*)(Qwb + (size_t)i * DH + quad * 8);
        qw1 = *(const bf16x8*)(Qwb + (size_t)i * DH + 32 + quad * 8);
        qr0 = *(const bf16x8*)(Qrb + (size_t)i * DH + quad * 8);
        qr1 = *(const bf16x8*)(Qrb + (size_t)i * DH + 32 + quad * 8);
    }

    float lpart[4] = {0.f, 0.f, 0.f, 0.f};
    f32x4 oacc[4] = {};

    const int ntiles = qt + 17;
    const int cbase = 15 - qt;  // global RR chunk of window start at t=0
    const int ptbase = 3 - wave;

    auto stage_kv = [&](int t) {
        const int j0 = t * 64;
        bf16* Kd = Ks[t & 1];
        bf16* Vd = Vs[t & 1];
        for (int issue = 0; issue < 2; ++issue) {
            int q = (issue * 4 + wave) * 64 + lane;
            int row = q >> 3, cs = (q & 7) ^ ((q >> 3) & 7);
            ldg2lds16(Kb + (size_t)(j0 + row) * DH + cs * 8,
                      Kd + (issue * 4 + wave) * 512);
            ldg2lds16(Vb + (size_t)row * KLEN + j0 + cs * 8,
                      Vd + (issue * 4 + wave) * 512);
        }
    };
    auto stage_rr = [&](int c) {  // load global 64-row chunk c into slot c%3
        bf16* Rd = RRing[c % 3];
        for (int issue = 0; issue < 2; ++issue) {
            int q = (issue * 4 + wave) * 64 + lane;
            int row = q >> 3, cs = (q & 7) ^ ((q >> 3) & 7);
            int pr = c * 64 + row;
            pr = pr > KLEN - 1 ? KLEN - 1 : pr;  // clamped rows feed masked cols
            ldg2lds16(Rb + (size_t)pr * DH + cs * 8, Rd + (issue * 4 + wave) * 512);
        }
    };

    stage_kv(0);
    stage_rr(cbase);
    stage_rr(cbase + 1);
    __syncthreads();

    for (int t = 0; t < ntiles; ++t) {
        const bf16* Kt = Ks[t & 1];
        const bf16* Vl = Vs[t & 1];
        const bf16* Rlo = RRing[(cbase + t) % 3];
        const bf16* Rhi = RRing[(cbase + t + 1) % 3];
        if (t + 1 < ntiles) {
            stage_kv(t + 1);
            stage_rr(cbase + t + 2);
        }

        // BD = Qr @ RRwindow^T (this wave's 5 pt tiles) -> UB compact
        for (int pi = 0; pi < 5; ++pi) {
            int pt = ptbase + pi;
            const bf16* Rsrc = (pt < 4) ? Rlo : Rhi;
            int rrow = (pt & 3) * 16 + l16;
            f32x4 bacc = {};
            bacc = MFMA16(qr0, frag8(Rsrc, rrow, quad), bacc);
            bacc = MFMA16(qr1, frag8(Rsrc, rrow, 4 + quad), bacc);
            for (int rr = 0; rr < 4; ++rr)
                UB[wave][(quad * 4 + rr) * 88 + pi * 16 + l16] = (bf16)bacc[rr];
        }

        // AC = Qw @ K^T
        f32x4 sacc[4];
        for (int nt = 0; nt < 4; ++nt) {
            f32x4 a = {};
            a = MFMA16(qw0, frag8(Kt, nt * 16 + l16, quad), a);
            a = MFMA16(qw1, frag8(Kt, nt * 16 + l16, 4 + quad), a);
            sacc[nt] = a;
        }

        // p = exp(AC+BD); only final tile needs the causal mask
        float sv[4][4];
        const bool lastt = (t == ntiles - 1);
        for (int nt = 0; nt < 4; ++nt)
            for (int rr = 0; rr < 4; ++rr) {
                int lr = quad * 4 + rr;
                int col = nt * 16 + l16 + 15 - lr;
                float bdv = (float)UB[wave][lr * 88 + col];
                float p = __expf(sacc[nt][rr] + bdv);
                if (lastt) {
                    int i = i0 + wave * 16 + lr;
                    int j = t * 64 + nt * 16 + l16;
                    if (j > i + ML) p = 0.f;
                }
                sv[nt][rr] = p;
                lpart[rr] += p;
            }

        // P: C-layout -> UB cols 0..63 (bds consumed) -> A-layout
        for (int nt = 0; nt < 4; ++nt)
            for (int rr = 0; rr < 4; ++rr)
                UB[wave][(quad * 4 + rr) * 88 + nt * 16 + l16] = (bf16)sv[nt][rr];

        for (int c = 0; c < 2; ++c) {
            bf16x8 pa = *(const bf16x8*)(&UB[wave][l16 * 88 + c * 32 + quad * 8]);
            for (int nt = 0; nt < 4; ++nt) {
                bf16x8 vb = frag8(Vl, nt * 16 + l16, c * 4 + quad);
                oacc[nt] = MFMA16(pa, vb, oacc[nt]);
            }
        }
        __syncthreads();  // prefetched t+1 complete + all reads of t done
    }

    // deferred l reduction (once, not per tile)
    float linv[4];
    for (int rr = 0; rr < 4; ++rr) {
        float v = lpart[rr];
        v += __shfl_xor(v, 1);
        v += __shfl_xor(v, 2);
        v += __shfl_xor(v, 4);
        v += __shfl_xor(v, 8);
        linv[rr] = 1.f / v;
    }

    for (int nt = 0; nt < 4; ++nt)
        for (int rr = 0; rr < 4; ++rr) {
            int i = i0 + wave * 16 + quad * 4 + rr;
            int d = nt * 16 + l16;
            AttO[((size_t)(b * QL + i)) * E + h * DH + d] =
                (bf16)(oacc[nt][rr] * linv[rr]);
        }
}

// ---------------------------------------------------------------- out proj
// split-K x2: z-half computes partial Xp[z] (fp32, no resid). ln_k sums.
// Single-buffer two-barrier staging (R9-frozen).
__global__ __launch_bounds__(256) void gemm_o(
    const bf16* __restrict__ A, const bf16* __restrict__ Bt,
    float* __restrict__ Xp) {
    __shared__ __align__(16) bf16 As[128 * 64];
    __shared__ __align__(16) bf16 Bs[128 * 64];
    const int tid = threadIdx.x;
    const int wave = tid >> 6, lane = tid & 63, quad = lane >> 4, l16 = lane & 15;
    const int bm = blockIdx.y * 128, bn = blockIdx.x * 128;
    const int kbase = blockIdx.z * 512;
    const int wm = (wave >> 1) * 64, wn = (wave & 1) * 64;

    f32x4 acc[4][4] = {};

    for (int s = 0; s < 8; ++s) {
        const int kk = kbase + s * 64;
        for (int issue = 0; issue < 4; ++issue) {
            int q = (issue * 4 + wave) * 64 + lane;
            int row = q >> 3, cs = (q & 7) ^ ((q >> 3) & 7);
            ldg2lds16(A + (size_t)(bm + row) * E + kk + cs * 8,
                      As + (issue * 4 + wave) * 512);
            ldg2lds16(Bt + (size_t)(bn + row) * E + kk + cs * 8,
                      Bs + (issue * 4 + wave) * 512);
        }
        __syncthreads();
        for (int ks = 0; ks < 64; ks += 32) {
            bf16x8 af[4], bfr[4];
            for (int mt = 0; mt < 4; ++mt)
                af[mt] = frag8(As, wm + mt * 16 + l16, (ks >> 3) + quad);
            for (int nt = 0; nt < 4; ++nt)
                bfr[nt] = frag8(Bs, wn + nt * 16 + l16, (ks >> 3) + quad);
            for (int mt = 0; mt < 4; ++mt)
                for (int nt = 0; nt < 4; ++nt)
                    acc[mt][nt] = MFMA16(af[mt], bfr[nt], acc[mt][nt]);
        }
        __syncthreads();
    }

    float* Xz = Xp + (size_t)blockIdx.z * 2048 * 1024;
    for (int mt = 0; mt < 4; ++mt)
        for (int nt = 0; nt < 4; ++nt)
            for (int rr = 0; rr < 4; ++rr) {
                int row = bm + wm + mt * 16 + quad * 4 + rr;
                int col = bn + wn + nt * 16 + l16;
                Xz[(size_t)row * E + col] = acc[mt][nt][rr];
            }
}

// ---------------------------------------------------------------- layernorm
// x = Xp0 + Xp1 + resid(w); out = LN(x)*gamma+beta
__global__ __launch_bounds__(256) void ln_k(const float* __restrict__ Xp,
                                            const float* __restrict__ resid,
                                            const float* __restrict__ gamma,
                                            const float* __restrict__ beta,
                                            float* __restrict__ out) {
    const int row = blockIdx.x;
    const int tid = threadIdx.x;
    const float* x0 = Xp + (size_t)row * E;
    const float* x1 = Xp + (size_t)2048 * 1024 + (size_t)row * E;
    const float* xr = resid + (size_t)row * E;
    float xv[4], s = 0.f, q = 0.f;
    for (int c = 0; c < 4; ++c) {
        int col = c * 256 + tid;
        float v = x0[col] + x1[col] + xr[col];
        xv[c] = v;
        s += v;
        q += v * v;
    }
    for (int off = 32; off > 0; off >>= 1) {
        s += __shfl_down(s, off);
        q += __shfl_down(q, off);
    }
    __shared__ float rs[4], rq[4];
    int wave = tid >> 6, lane = tid & 63;
    if (lane == 0) { rs[wave] = s; rq[wave] = q; }
    __syncthreads();
    float S = rs[0] + rs[1] + rs[2] + rs[3];
    float Q = rq[0] + rq[1] + rq[2] + rq[3];
    float mean = S * (1.f / E);
    float var = fmaxf(Q * (1.f / E) - mean * mean, 0.f);
    float rstd = rsqrtf(var + 1e-3f);
    for (int c = 0; c < 4; ++c) {
        int col = c * 256 + tid;
        out[(size_t)row * E + col] =
            (xv[c] - mean) * rstd * gamma[col] + beta[col];
    }
}

// ---------------------------------------------------------------- launch
extern "C" void kernel_launch(void* const* d_in, const int* in_sizes, int n_in,
                              void* d_out, int out_size, void* d_ws,
                              size_t ws_size, hipStream_t stream) {
    (void)in_sizes; (void)n_in; (void)out_size; (void)ws_size;
    const float* w = (const float*)d_in[0];
    const float* r = (const float*)d_in[1];
    const float* rwb = (const float*)d_in[3];
    const float* rrb = (const float*)d_in[4];
    const float* member = (const float*)d_in[5];
    const float* Wq = (const float*)d_in[6];
    const float* Wk = (const float*)d_in[7];
    const float* Wv = (const float*)d_in[8];
    const float* Wr = (const float*)d_in[9];
    const float* Wo = (const float*)d_in[10];
    const float* gamma = (const float*)d_in[11];
    const float* beta = (const float*)d_in[12];
    float* out = (float*)d_out;

    char* ws = (char*)d_ws;
    const size_t MB = 1024 * 1024;
    bf16* WqT = (bf16*)(ws + 0 * MB);   // 0-8: WqT/WkT/WvT/WrT (dead after proj)
    bf16* WkT = (bf16*)(ws + 2 * MB);
    bf16* WvT = (bf16*)(ws + 4 * MB);
    bf16* WrT = (bf16*)(ws + 6 * MB);
    bf16* WoT = (bf16*)(ws + 8 * MB);   // live until gemm_o
    bf16* cat = (bf16*)(ws + 10 * MB);  // 10-18; dead after proj_k
    bf16* AttO = (bf16*)(ws + 14 * MB); // 14-18 (over cat 2nd half)
    bf16* Qw = (bf16*)(ws + 18 * MB);
    bf16* Qr = (bf16*)(ws + 22 * MB);
    float* Xp = (float*)(ws + 18 * MB); // 18-34 over Qw/Qr/Kh (dead after attn)
    bf16* Kh = (bf16*)(ws + 26 * MB);
    bf16* Vt = (bf16*)(ws + 34 * MB);
    bf16* RRh = (bf16*)(ws + 42 * MB);
    // high-water: 46 MB

    pre_k<<<9216, 256, 0, stream>>>(Wq, Wk, Wv, Wr, Wo, member, w, WqT, WkT,
                                    WvT, WrT, WoT, cat);

    proj_k<<<768, 256, 0, stream>>>(cat, r, WqT, WkT, WvT, WrT, rwb, rrb, Qw,
                                    Qr, Kh, Vt, RRh);

    attn_k<<<512, 256, 0, stream>>>(Qw, Qr, Kh, Vt, RRh, AttO);

    gemm_o<<<dim3(8, 16, 2), 256, 0, stream>>>(AttO, WoT, Xp);
    ln_k<<<2048, 256, 0, stream>>>(Xp, w, gamma, beta, out);
}

// Round 13
// 259.568 us; speedup vs baseline: 2.0054x; 1.0104x over previous
//
#include <hip/hip_runtime.h>

// Transformer-XL relative multi-head attention + LayerNorm.
// Inputs/outputs fp32; internal MFMA compute in bf16.
// B=2, H=16, D=64, E=1024, QL=1024, ML=1024, KLEN=2048.
// rel_shift identity: unmasked (j<=i+ML): BDshift[i,j] = BD[i, j-i+QL-1].
// R13: single change vs R12 — attn_k's BD rel-shift gather moved from an
// LDS round-trip (20 ds_write_b16 + 16 ds_read_u16 + cvts per thread/tile)
// to in-register cross-lane shuffles: dest (quad,l16,rr,nt) = lane
// quad*16+((l16-lr-1)&15), reg bacc[nt+(l16>lr)][rr]. 20 bpermutes + selects,
// no store->load hazard, BD stays fp32. UB now holds P only (layout frozen).
// proj_k/gemm_o/ln_k/pre_k byte-identical to R12.

typedef __bf16 bf16;
typedef __bf16 bf16x4 __attribute__((ext_vector_type(4)));
typedef __bf16 bf16x8 __attribute__((ext_vector_type(8)));
typedef float f32x4 __attribute__((ext_vector_type(4)));

#define MFMA16(a, b, c) __builtin_amdgcn_mfma_f32_16x16x32_bf16((a), (b), (c), 0, 0, 0)

constexpr int E = 1024;
constexpr int NH = 16;
constexpr int DH = 64;
constexpr int QL = 1024;
constexpr int ML = 1024;
constexpr int KLEN = 2048;

// async 16B global->LDS. LDS dest is wave-uniform base + lane*16.
__device__ __forceinline__ void ldg2lds16(const bf16* g, bf16* l) {
    __builtin_amdgcn_global_load_lds(
        (const __attribute__((address_space(1))) unsigned int*)g,
        (__attribute__((address_space(3))) unsigned int*)l, 16, 0, 0);
}

// read a b128 fragment from an unpadded 64-col swizzled tile.
// physical 16B-chunk = logical chunk ^ (row & 7).
__device__ __forceinline__ bf16x8 frag8(const bf16* t, int row, int ch) {
    return *(const bf16x8*)(t + row * 64 + ((ch ^ (row & 7)) << 3));
}

// ---------------------------------------------------------------- pre
// blocks 0..5119: 5 weight transposes (WT[n][k] = bf16(W[k][n]))
// blocks 5120..9215: cat[b][jj][e] = bf16(concat(member, w))
__global__ void pre_k(const float* __restrict__ Wq, const float* __restrict__ Wk,
                      const float* __restrict__ Wv, const float* __restrict__ Wr,
                      const float* __restrict__ Wo, const float* __restrict__ member,
                      const float* __restrict__ w, bf16* __restrict__ WqT,
                      bf16* __restrict__ WkT, bf16* __restrict__ WvT,
                      bf16* __restrict__ WrT, bf16* __restrict__ WoT,
                      bf16* __restrict__ cat) {
    const int id = blockIdx.x;
    const int tid = threadIdx.x;
    __shared__ float t[32][33];
    if (id < 5120) {
        const float* W; bf16* WT;
        switch (id >> 10) {
            case 0: W = Wq; WT = WqT; break;
            case 1: W = Wk; WT = WkT; break;
            case 2: W = Wv; WT = WvT; break;
            case 3: W = Wr; WT = WrT; break;
            default: W = Wo; WT = WoT; break;
        }
        int xy = id & 1023;
        int bx = (xy & 31) * 32, by = (xy >> 5) * 32;
        int x = tid & 31, y = tid >> 5;
        for (int yy = y; yy < 32; yy += 8)
            t[yy][x] = W[(by + yy) * E + bx + x];
        __syncthreads();
        for (int yy = y; yy < 32; yy += 8)
            WT[(bx + yy) * E + by + x] = (bf16)t[x][yy];
    } else {
        int row = id - 5120;
        int b = row >> 11, jj = row & 2047;
        const float* src = (jj < ML) ? member + ((size_t)(b * ML + jj)) * E
                                     : w + ((size_t)(b * QL + (jj - ML))) * E;
        float4 f = *(const float4*)(src + tid * 4);
        bf16x4 o;
        o[0] = (bf16)f.x; o[1] = (bf16)f.y; o[2] = (bf16)f.z; o[3] = (bf16)f.w;
        *(bf16x4*)(cat + (size_t)row * E + tid * 4) = o;
    }
}

// ---------------------------------------------------------------- projections
// EXACT R9 body. Single-buffer two-barrier staging.
// zone 0: Q (+biases, *1/32 folded -> Qw/Qr [b][h][i][d])
// zone 1: K -> Kh [b][h][j][d];  zone 2: V -> Vt [b][h][d][j];  zone 3: R -> RRh
__global__ __launch_bounds__(256) void proj_k(
    const bf16* __restrict__ cat, const float* __restrict__ r,
    const bf16* __restrict__ WqT, const bf16* __restrict__ WkT,
    const bf16* __restrict__ WvT, const bf16* __restrict__ WrT,
    const float* __restrict__ rwb, const float* __restrict__ rrb,
    bf16* __restrict__ Qw, bf16* __restrict__ Qr, bf16* __restrict__ Kh,
    bf16* __restrict__ Vt, bf16* __restrict__ RRh) {
    __shared__ __align__(16) bf16 As[128 * 64];
    __shared__ __align__(16) bf16 Bs[128 * 64];
    const int tid = threadIdx.x;
    const int wave = tid >> 6, lane = tid & 63, quad = lane >> 4, l16 = lane & 15;

    int id = blockIdx.x, zone, base;
    if (id < 128) { zone = 0; base = 0; }
    else if (id < 384) { zone = 1; base = 128; }
    else if (id < 640) { zone = 2; base = 384; }
    else { zone = 3; base = 640; }
    const int lid = id - base;
    const int bn = (lid & 7) * 128, bm = (lid >> 3) * 128;
    const bf16* Bt = (zone == 0) ? WqT : (zone == 1) ? WkT : (zone == 2) ? WvT : WrT;
    const int wm = (wave >> 1) * 64, wn = (wave & 1) * 64;

    f32x4 acc[4][4] = {};

    for (int kk = 0; kk < E; kk += 64) {
        if (zone == 3) {  // fp32 A: manual convert+write (swizzled slots)
            int srw = tid >> 3, cch = tid & 7;
            for (int c = 0; c < 4; ++c) {
                int row = c * 32 + srw;
                const float* ap = r + (size_t)(bm + row) * E + kk + cch * 8;
                float4 f0 = *(const float4*)ap;
                float4 f1 = *(const float4*)(ap + 4);
                bf16x8 v;
                v[0] = (bf16)f0.x; v[1] = (bf16)f0.y; v[2] = (bf16)f0.z; v[3] = (bf16)f0.w;
                v[4] = (bf16)f1.x; v[5] = (bf16)f1.y; v[6] = (bf16)f1.z; v[7] = (bf16)f1.w;
                *(bf16x8*)(As + row * 64 + ((cch ^ (row & 7)) << 3)) = v;
            }
        } else {
            for (int issue = 0; issue < 4; ++issue) {
                int q = (issue * 4 + wave) * 64 + lane;
                int row = q >> 3, cs = (q & 7) ^ ((q >> 3) & 7);
                int gm = bm + row;
                const bf16* ap;
                if (zone == 0) {
                    int b = gm >> 10;
                    ap = cat + ((size_t)(b * 2048 + 1024 + (gm & 1023))) * E;
                } else {
                    ap = cat + (size_t)gm * E;
                }
                ldg2lds16(ap + kk + cs * 8, As + (issue * 4 + wave) * 512);
            }
        }
        for (int issue = 0; issue < 4; ++issue) {
            int q = (issue * 4 + wave) * 64 + lane;
            int row = q >> 3, cs = (q & 7) ^ ((q >> 3) & 7);
            ldg2lds16(Bt + (size_t)(bn + row) * E + kk + cs * 8,
                      Bs + (issue * 4 + wave) * 512);
        }
        __syncthreads();
        for (int ks = 0; ks < 64; ks += 32) {
            bf16x8 af[4], bfr[4];
            for (int mt = 0; mt < 4; ++mt)
                af[mt] = frag8(As, wm + mt * 16 + l16, (ks >> 3) + quad);
            for (int nt = 0; nt < 4; ++nt)
                bfr[nt] = frag8(Bs, wn + nt * 16 + l16, (ks >> 3) + quad);
            for (int mt = 0; mt < 4; ++mt)
                for (int nt = 0; nt < 4; ++nt)
                    acc[mt][nt] = MFMA16(af[mt], bfr[nt], acc[mt][nt]);
        }
        __syncthreads();
    }

    if (zone == 2) {
        // Vt[b][h][d][j]: per-wave 64x64 swizzled LDS transpose, then b128 stores.
        bf16* buf = ((wave < 2) ? As : Bs) + (wave & 1) * 4096;
        for (int mt = 0; mt < 4; ++mt)
            for (int nt = 0; nt < 4; ++nt)
                for (int rr = 0; rr < 4; ++rr) {
                    int lr = mt * 16 + quad * 4 + rr;  // local j
                    int lc = nt * 16 + l16;            // local d
                    buf[lr * 64 + (((lc >> 3) ^ (lr & 7)) << 3) + (lc & 7)] =
                        (bf16)acc[mt][nt][rr];
                }
        int h = (bn + wn) >> 6;
        int gmw = bm + wm;
        int b = gmw >> 11, jb = gmw & 2047;
        for (int dp = 0; dp < 8; ++dp) {
            int dl = dp * 8 + (lane >> 3);
            int jl = (lane & 7) * 8;
            bf16x8 tmp;
            for (int jj = 0; jj < 8; ++jj) {
                int rw = jl + jj;
                tmp[jj] = buf[rw * 64 + (((dl >> 3) ^ (rw & 7)) << 3) + (dl & 7)];
            }
            *(bf16x8*)(Vt + (((size_t)(b * NH + h) * DH + dl) * KLEN) + jb + jl) = tmp;
        }
        return;
    }

    for (int mt = 0; mt < 4; ++mt)
        for (int nt = 0; nt < 4; ++nt)
            for (int rr = 0; rr < 4; ++rr) {
                int row = bm + wm + mt * 16 + quad * 4 + rr;
                int col = bn + wn + nt * 16 + l16;
                float v = acc[mt][nt][rr];
                if (zone == 0) {
                    int b = row >> 10, i = row & 1023;
                    int h = col >> 6, d = col & 63;
                    size_t o = (((size_t)(b * NH + h) * QL) + i) * DH + d;
                    Qw[o] = (bf16)((v + rwb[col]) * 0.03125f);  // fold 1/sqrt(E)
                    Qr[o] = (bf16)((v + rrb[col]) * 0.03125f);
                } else if (zone == 1) {
                    int b = row >> 11, j = row & 2047;
                    int h = col >> 6, d = col & 63;
                    Kh[(((size_t)(b * NH + h) * KLEN) + j) * DH + d] = (bf16)v;
                } else {
                    int h = col >> 6, d = col & 63;
                    RRh[(((size_t)h * KLEN) + row) * DH + d] = (bf16)v;
                }
            }
}

// ---------------------------------------------------------------- attention
// R5/R9 structure; BD gather now in-register via cross-lane shuffles.
// 512 blocks, 256 thr, each wave 16 q-rows. Fixed-shift softmax (M=0).
// K/V double-buffered; RR 3-slot rolling ring; UB holds P only.
__global__ __launch_bounds__(256) void attn_k(
    const bf16* __restrict__ Qw, const bf16* __restrict__ Qr,
    const bf16* __restrict__ Kh, const bf16* __restrict__ Vt,
    const bf16* __restrict__ RRh, bf16* __restrict__ AttO) {
    __shared__ __align__(16) bf16 Ks[2][64 * 64];
    __shared__ __align__(16) bf16 Vs[2][64 * 64];
    __shared__ __align__(16) bf16 RRing[3][64 * 64];
    __shared__ __align__(16) bf16 UB[4][16 * 88];  // per-wave P (A-layout src)

    const int tid = threadIdx.x;
    const int wave = tid >> 6, lane = tid & 63, quad = lane >> 4, l16 = lane & 15;
    const int id = blockIdx.x;
    const int b = id >> 8, h = (id >> 4) & 15;
    const int qt = (id < 256) ? (id & 15) : (15 - (id & 15));
    const int i0 = qt * 64;

    const bf16* Qwb = Qw + ((size_t)(b * NH + h) * QL) * DH;
    const bf16* Qrb = Qr + ((size_t)(b * NH + h) * QL) * DH;
    const bf16* Kb = Kh + ((size_t)(b * NH + h) * KLEN) * DH;
    const bf16* Vb = Vt + ((size_t)(b * NH + h) * DH) * KLEN;  // [d][j]
    const bf16* Rb = RRh + ((size_t)h * KLEN) * DH;

    bf16x8 qw0, qw1, qr0, qr1;
    {
        int i = i0 + wave * 16 + l16;
        qw0 = *(const bf16x8*)(Qwb + (size_t)i * DH + quad * 8);
        qw1 = *(const bf16x8*)(Qwb + (size_t)i * DH + 32 + quad * 8);
        qr0 = *(const bf16x8*)(Qrb + (size_t)i * DH + quad * 8);
        qr1 = *(const bf16x8*)(Qrb + (size_t)i * DH + 32 + quad * 8);
    }

    float lpart[4] = {0.f, 0.f, 0.f, 0.f};
    f32x4 oacc[4] = {};

    const int ntiles = qt + 17;
    const int cbase = 15 - qt;  // global RR chunk of window start at t=0
    const int ptbase = 3 - wave;

    auto stage_kv = [&](int t) {
        const int j0 = t * 64;
        bf16* Kd = Ks[t & 1];
        bf16* Vd = Vs[t & 1];
        for (int issue = 0; issue < 2; ++issue) {
            int q = (issue * 4 + wave) * 64 + lane;
            int row = q >> 3, cs = (q & 7) ^ ((q >> 3) & 7);
            ldg2lds16(Kb + (size_t)(j0 + row) * DH + cs * 8,
                      Kd + (issue * 4 + wave) * 512);
            ldg2lds16(Vb + (size_t)row * KLEN + j0 + cs * 8,
                      Vd + (issue * 4 + wave) * 512);
        }
    };
    auto stage_rr = [&](int c) {  // load global 64-row chunk c into slot c%3
        bf16* Rd = RRing[c % 3];
        for (int issue = 0; issue < 2; ++issue) {
            int q = (issue * 4 + wave) * 64 + lane;
            int row = q >> 3, cs = (q & 7) ^ ((q >> 3) & 7);
            int pr = c * 64 + row;
            pr = pr > KLEN - 1 ? KLEN - 1 : pr;  // clamped rows feed masked cols
            ldg2lds16(Rb + (size_t)pr * DH + cs * 8, Rd + (issue * 4 + wave) * 512);
        }
    };

    stage_kv(0);
    stage_rr(cbase);
    stage_rr(cbase + 1);
    __syncthreads();

    for (int t = 0; t < ntiles; ++t) {
        const bf16* Kt = Ks[t & 1];
        const bf16* Vl = Vs[t & 1];
        const bf16* Rlo = RRing[(cbase + t) % 3];
        const bf16* Rhi = RRing[(cbase + t + 1) % 3];
        if (t + 1 < ntiles) {
            stage_kv(t + 1);
            stage_rr(cbase + t + 2);
        }

        // BD = Qr @ RRwindow^T (this wave's 5 pt tiles) -> registers
        f32x4 bacc[5];
        for (int pi = 0; pi < 5; ++pi) {
            int pt = ptbase + pi;
            const bf16* Rsrc = (pt < 4) ? Rlo : Rhi;
            int rrow = (pt & 3) * 16 + l16;
            f32x4 a = {};
            a = MFMA16(qr0, frag8(Rsrc, rrow, quad), a);
            a = MFMA16(qr1, frag8(Rsrc, rrow, 4 + quad), a);
            bacc[pi] = a;
        }

        // AC = Qw @ K^T
        f32x4 sacc[4];
        for (int nt = 0; nt < 4; ++nt) {
            f32x4 a = {};
            a = MFMA16(qw0, frag8(Kt, nt * 16 + l16, quad), a);
            a = MFMA16(qw1, frag8(Kt, nt * 16 + l16, 4 + quad), a);
            sacc[nt] = a;
        }

        // p = exp(AC+BD); BD rel-shift gather via cross-lane shuffles:
        // dest (quad,l16,rr,nt) <- lane quad*16+((l16-lr-1)&15),
        //                          reg bacc[nt + (l16>lr)][rr].
        float sv[4][4];
        const bool lastt = (t == ntiles - 1);
        for (int rr = 0; rr < 4; ++rr) {
            const int lr = quad * 4 + rr;
            const int srcl = quad * 16 + ((l16 - lr - 1) & 15);
            float g[5];
            for (int pi = 0; pi < 5; ++pi) g[pi] = __shfl(bacc[pi][rr], srcl);
            const bool hi = (l16 > lr);
            for (int nt = 0; nt < 4; ++nt) {
                float bdv = hi ? g[nt + 1] : g[nt];
                float p = __expf(sacc[nt][rr] + bdv);
                if (lastt) {
                    int i = i0 + wave * 16 + lr;
                    int j = t * 64 + nt * 16 + l16;
                    if (j > i + ML) p = 0.f;
                }
                sv[nt][rr] = p;
                lpart[rr] += p;
            }
        }

        // P: C-layout -> UB -> A-layout
        for (int nt = 0; nt < 4; ++nt)
            for (int rr = 0; rr < 4; ++rr)
                UB[wave][(quad * 4 + rr) * 88 + nt * 16 + l16] = (bf16)sv[nt][rr];

        for (int c = 0; c < 2; ++c) {
            bf16x8 pa = *(const bf16x8*)(&UB[wave][l16 * 88 + c * 32 + quad * 8]);
            for (int nt = 0; nt < 4; ++nt) {
                bf16x8 vb = frag8(Vl, nt * 16 + l16, c * 4 + quad);
                oacc[nt] = MFMA16(pa, vb, oacc[nt]);
            }
        }
        __syncthreads();  // prefetched t+1 complete + all reads of t done
    }

    // deferred l reduction (once, not per tile)
    float linv[4];
    for (int rr = 0; rr < 4; ++rr) {
        float v = lpart[rr];
        v += __shfl_xor(v, 1);
        v += __shfl_xor(v, 2);
        v += __shfl_xor(v, 4);
        v += __shfl_xor(v, 8);
        linv[rr] = 1.f / v;
    }

    for (int nt = 0; nt < 4; ++nt)
        for (int rr = 0; rr < 4; ++rr) {
            int i = i0 + wave * 16 + quad * 4 + rr;
            int d = nt * 16 + l16;
            AttO[((size_t)(b * QL + i)) * E + h * DH + d] =
                (bf16)(oacc[nt][rr] * linv[rr]);
        }
}

// ---------------------------------------------------------------- out proj
// split-K x2: z-half computes partial Xp[z] (fp32, no resid). ln_k sums.
// Single-buffer two-barrier staging (R9-frozen).
__global__ __launch_bounds__(256) void gemm_o(
    const bf16* __restrict__ A, const bf16* __restrict__ Bt,
    float* __restrict__ Xp) {
    __shared__ __align__(16) bf16 As[128 * 64];
    __shared__ __align__(16) bf16 Bs[128 * 64];
    const int tid = threadIdx.x;
    const int wave = tid >> 6, lane = tid & 63, quad = lane >> 4, l16 = lane & 15;
    const int bm = blockIdx.y * 128, bn = blockIdx.x * 128;
    const int kbase = blockIdx.z * 512;
    const int wm = (wave >> 1) * 64, wn = (wave & 1) * 64;

    f32x4 acc[4][4] = {};

    for (int s = 0; s < 8; ++s) {
        const int kk = kbase + s * 64;
        for (int issue = 0; issue < 4; ++issue) {
            int q = (issue * 4 + wave) * 64 + lane;
            int row = q >> 3, cs = (q & 7) ^ ((q >> 3) & 7);
            ldg2lds16(A + (size_t)(bm + row) * E + kk + cs * 8,
                      As + (issue * 4 + wave) * 512);
            ldg2lds16(Bt + (size_t)(bn + row) * E + kk + cs * 8,
                      Bs + (issue * 4 + wave) * 512);
        }
        __syncthreads();
        for (int ks = 0; ks < 64; ks += 32) {
            bf16x8 af[4], bfr[4];
            for (int mt = 0; mt < 4; ++mt)
                af[mt] = frag8(As, wm + mt * 16 + l16, (ks >> 3) + quad);
            for (int nt = 0; nt < 4; ++nt)
                bfr[nt] = frag8(Bs, wn + nt * 16 + l16, (ks >> 3) + quad);
            for (int mt = 0; mt < 4; ++mt)
                for (int nt = 0; nt < 4; ++nt)
                    acc[mt][nt] = MFMA16(af[mt], bfr[nt], acc[mt][nt]);
        }
        __syncthreads();
    }

    float* Xz = Xp + (size_t)blockIdx.z * 2048 * 1024;
    for (int mt = 0; mt < 4; ++mt)
        for (int nt = 0; nt < 4; ++nt)
            for (int rr = 0; rr < 4; ++rr) {
                int row = bm + wm + mt * 16 + quad * 4 + rr;
                int col = bn + wn + nt * 16 + l16;
                Xz[(size_t)row * E + col] = acc[mt][nt][rr];
            }
}

// ---------------------------------------------------------------- layernorm
// x = Xp0 + Xp1 + resid(w); out = LN(x)*gamma+beta
__global__ __launch_bounds__(256) void ln_k(const float* __restrict__ Xp,
                                            const float* __restrict__ resid,
                                            const float* __restrict__ gamma,
                                            const float* __restrict__ beta,
                                            float* __restrict__ out) {
    const int row = blockIdx.x;
    const int tid = threadIdx.x;
    const float* x0 = Xp + (size_t)row * E;
    const float* x1 = Xp + (size_t)2048 * 1024 + (size_t)row * E;
    const float* xr = resid + (size_t)row * E;
    float xv[4], s = 0.f, q = 0.f;
    for (int c = 0; c < 4; ++c) {
        int col = c * 256 + tid;
        float v = x0[col] + x1[col] + xr[col];
        xv[c] = v;
        s += v;
        q += v * v;
    }
    for (int off = 32; off > 0; off >>= 1) {
        s += __shfl_down(s, off);
        q += __shfl_down(q, off);
    }
    __shared__ float rs[4], rq[4];
    int wave = tid >> 6, lane = tid & 63;
    if (lane == 0) { rs[wave] = s; rq[wave] = q; }
    __syncthreads();
    float S = rs[0] + rs[1] + rs[2] + rs[3];
    float Q = rq[0] + rq[1] + rq[2] + rq[3];
    float mean = S * (1.f / E);
    float var = fmaxf(Q * (1.f / E) - mean * mean, 0.f);
    float rstd = rsqrtf(var + 1e-3f);
    for (int c = 0; c < 4; ++c) {
        int col = c * 256 + tid;
        out[(size_t)row * E + col] =
            (xv[c] - mean) * rstd * gamma[col] + beta[col];
    }
}

// ---------------------------------------------------------------- launch
extern "C" void kernel_launch(void* const* d_in, const int* in_sizes, int n_in,
                              void* d_out, int out_size, void* d_ws,
                              size_t ws_size, hipStream_t stream) {
    (void)in_sizes; (void)n_in; (void)out_size; (void)ws_size;
    const float* w = (const float*)d_in[0];
    const float* r = (const float*)d_in[1];
    const float* rwb = (const float*)d_in[3];
    const float* rrb = (const float*)d_in[4];
    const float* member = (const float*)d_in[5];
    const float* Wq = (const float*)d_in[6];
    const float* Wk = (const float*)d_in[7];
    const float* Wv = (const float*)d_in[8];
    const float* Wr = (const float*)d_in[9];
    const float* Wo = (const float*)d_in[10];
    const float* gamma = (const float*)d_in[11];
    const float* beta = (const float*)d_in[12];
    float* out = (float*)d_out;

    char* ws = (char*)d_ws;
    const size_t MB = 1024 * 1024;
    bf16* WqT = (bf16*)(ws + 0 * MB);   // 0-8: WqT/WkT/WvT/WrT (dead after proj)
    bf16* WkT = (bf16*)(ws + 2 * MB);
    bf16* WvT = (bf16*)(ws + 4 * MB);
    bf16* WrT = (bf16*)(ws + 6 * MB);
    bf16* WoT = (bf16*)(ws + 8 * MB);   // live until gemm_o
    bf16* cat = (bf16*)(ws + 10 * MB);  // 10-18; dead after proj_k
    bf16* AttO = (bf16*)(ws + 14 * MB); // 14-18 (over cat 2nd half)
    bf16* Qw = (bf16*)(ws + 18 * MB);
    bf16* Qr = (bf16*)(ws + 22 * MB);
    float* Xp = (float*)(ws + 18 * MB); // 18-34 over Qw/Qr/Kh (dead after attn)
    bf16* Kh = (bf16*)(ws + 26 * MB);
    bf16* Vt = (bf16*)(ws + 34 * MB);
    bf16* RRh = (bf16*)(ws + 42 * MB);
    // high-water: 46 MB

    pre_k<<<9216, 256, 0, stream>>>(Wq, Wk, Wv, Wr, Wo, member, w, WqT, WkT,
                                    WvT, WrT, WoT, cat);

    proj_k<<<768, 256, 0, stream>>>(cat, r, WqT, WkT, WvT, WrT, rwb, rrb, Qw,
                                    Qr, Kh, Vt, RRh);

    attn_k<<<512, 256, 0, stream>>>(Qw, Qr, Kh, Vt, RRh, AttO);

    gemm_o<<<dim3(8, 16, 2), 256, 0, stream>>>(AttO, WoT, Xp);
    ln_k<<<2048, 256, 0, stream>>>(Xp, w, gamma, beta, out);
}